// Round 1
// baseline (1152.991 us; speedup 1.0000x reference)
//
#include <hip/hip_runtime.h>
#include <hip/hip_bf16.h>

#define H 64
#define H3 192

__device__ __forceinline__ float sigmoidf_(float x) {
    return 1.0f / (1.0f + __expf(-x));
}
__device__ __forceinline__ float tanhf_(float x) {
    // safe fast tanh: 1 - 2/(e^{2x}+1); handles +/- inf limits correctly
    float e = __expf(2.0f * x);
    return 1.0f - 2.0f / (e + 1.0f);
}

// ---------------------------------------------------------------------------
// K1: h = features @ W_in + b_in; also a[n] = h.We[:64], b[n] = h.We[64:]
// thread-per-node
__global__ __launch_bounds__(256) void input_gates_kernel(
    const float* __restrict__ feat, const float* __restrict__ Win,
    const float* __restrict__ bin, const float* __restrict__ Wg,
    float* __restrict__ h, float* __restrict__ a_gate, float* __restrict__ b_gate,
    int N)
{
    __shared__ float sWin[16 * H];
    __shared__ float sbin[H];
    __shared__ float sWg[2 * H];
    int t = threadIdx.x;
    for (int i = t; i < 16 * H; i += 256) sWin[i] = Win[i];
    if (t < H) sbin[t] = bin[t];
    if (t < 2 * H) sWg[t] = Wg[t];
    __syncthreads();

    int n = blockIdx.x * 256 + t;
    if (n >= N) return;

    float f[16];
    const float4* fr = (const float4*)(feat + (size_t)n * 16);
#pragma unroll
    for (int i = 0; i < 4; i++) {
        float4 v = fr[i];
        f[4 * i + 0] = v.x; f[4 * i + 1] = v.y; f[4 * i + 2] = v.z; f[4 * i + 3] = v.w;
    }
    float a = 0.f, b = 0.f;
    float* hrow = h + (size_t)n * H;
    for (int j = 0; j < H; j++) {
        float hj = sbin[j];
#pragma unroll
        for (int k = 0; k < 16; k++) hj += f[k] * sWin[k * H + j];
        hrow[j] = hj;
        a += hj * sWg[j];
        b += hj * sWg[H + j];
    }
    a_gate[n] = a;
    b_gate[n] = b;
}

// ---------------------------------------------------------------------------
// CSR build: histogram of dst, exclusive scan, scatter src by dst
__global__ __launch_bounds__(256) void hist_kernel(
    const int* __restrict__ dst, int* __restrict__ deg, int E)
{
    int e = blockIdx.x * 256 + threadIdx.x;
    if (e < E) atomicAdd(&deg[dst[e]], 1);
}

__global__ __launch_bounds__(1024) void scan_kernel(
    const int* __restrict__ deg, int* __restrict__ offsets,
    int* __restrict__ counters, int N, int E)
{
    __shared__ int sums[1024];
    int t = threadIdx.x;
    int chunk = (N + 1023) >> 10;
    int beg = t * chunk;
    int end = beg + chunk; if (end > N) end = N;
    if (beg > N) beg = N;
    int s = 0;
    for (int i = beg; i < end; i++) s += deg[i];
    sums[t] = s;
    __syncthreads();
    // Hillis-Steele inclusive scan
    for (int off = 1; off < 1024; off <<= 1) {
        int v = (t >= off) ? sums[t - off] : 0;
        __syncthreads();
        sums[t] += v;
        __syncthreads();
    }
    int prefix = (t == 0) ? 0 : sums[t - 1];
    for (int i = beg; i < end; i++) {
        offsets[i] = prefix;
        counters[i] = prefix;
        prefix += deg[i];
    }
    if (t == 0) offsets[N] = E;
}

__global__ __launch_bounds__(256) void scatter_kernel(
    const int* __restrict__ src, const int* __restrict__ dst,
    int* __restrict__ counters, int* __restrict__ csr_src, int E)
{
    int e = blockIdx.x * 256 + threadIdx.x;
    if (e >= E) return;
    int d = dst[e];
    int pos = atomicAdd(&counters[d], 1);
    csr_src[pos] = src[e];
}

// ---------------------------------------------------------------------------
// Aggregate: h_new[v] = sum_{e: dst[e]==v} sigmoid(a[src]+b[v]+be) * h[src]
// wave-per-node, lane = feature component
__global__ __launch_bounds__(256) void aggregate_kernel(
    const float* __restrict__ h, const float* __restrict__ a_gate,
    const float* __restrict__ b_gate, const int* __restrict__ offsets,
    const int* __restrict__ csr_src, const float* __restrict__ b_edge,
    float* __restrict__ h_new, int N)
{
    int wid = threadIdx.x >> 6;
    int lane = threadIdx.x & 63;
    int v = blockIdx.x * 4 + wid;
    if (v >= N) return;

    int beg = offsets[v];
    int end = offsets[v + 1];
    float bv = b_gate[v] + b_edge[0];
    float acc = 0.f;

    for (int cs = beg; cs < end; cs += 64) {
        int m = end - cs; if (m > 64) m = 64;
        int u = 0; float w = 0.f;
        if (lane < m) {
            u = csr_src[cs + lane];
            w = sigmoidf_(a_gate[u] + bv);
        }
        for (int j = 0; j < m; j++) {
            int uj = __shfl(u, j);
            float wj = __shfl(w, j);
            acc += wj * h[(size_t)uj * H + lane];
        }
    }
    h_new[(size_t)v * H + lane] = acc;
}

// ---------------------------------------------------------------------------
// GRU cell (torch layout), thread-per-node, W in LDS (broadcast reads).
// Epilogue: gates a[n], b[n] for the next stage using Wg (W_edge or W_pred).
__global__ __launch_bounds__(256, 1) void gru_kernel(
    const float* __restrict__ x_in, float* __restrict__ h,
    const float* __restrict__ Wih, const float* __restrict__ Whh,
    const float* __restrict__ bih, const float* __restrict__ bhh,
    const float* __restrict__ Wg,
    float* __restrict__ a_gate, float* __restrict__ b_gate, int N)
{
    __shared__ float sWih[H3 * H];
    __shared__ float sWhh[H3 * H];
    __shared__ float sbih[H3];
    __shared__ float sbhh[H3];
    __shared__ float sWg[2 * H];

    int t = threadIdx.x;
    {
        const float4* a4 = (const float4*)Wih;
        const float4* b4 = (const float4*)Whh;
        float4* s4 = (float4*)sWih;
        float4* d4 = (float4*)sWhh;
        for (int i = t; i < H3 * H / 4; i += 256) { s4[i] = a4[i]; d4[i] = b4[i]; }
        if (t < H3) { sbih[t] = bih[t]; sbhh[t] = bhh[t]; }
        if (t < 2 * H) sWg[t] = Wg[t];
    }
    __syncthreads();

    int n = blockIdx.x * 256 + t;
    if (n >= N) return;

    float x[H], hp[H];
    const float4* xr = (const float4*)(x_in + (size_t)n * H);
    const float4* hr = (const float4*)(h + (size_t)n * H);
#pragma unroll
    for (int i = 0; i < H / 4; i++) {
        float4 v = xr[i];
        x[4 * i + 0] = v.x; x[4 * i + 1] = v.y; x[4 * i + 2] = v.z; x[4 * i + 3] = v.w;
        float4 w = hr[i];
        hp[4 * i + 0] = w.x; hp[4 * i + 1] = w.y; hp[4 * i + 2] = w.z; hp[4 * i + 3] = w.w;
    }

    float a = 0.f, b = 0.f;
    float* hrow = h + (size_t)n * H;
    for (int j = 0; j < H; j++) {
        float gir = sbih[j], giz = sbih[j + H], gin = sbih[j + 2 * H];
        float ghr = sbhh[j], ghz = sbhh[j + H], ghn = sbhh[j + 2 * H];
        const float* wr = &sWih[j * H];
        const float* wz = &sWih[(j + H) * H];
        const float* wn = &sWih[(j + 2 * H) * H];
        const float* vr = &sWhh[j * H];
        const float* vz = &sWhh[(j + H) * H];
        const float* vn = &sWhh[(j + 2 * H) * H];
#pragma unroll
        for (int k = 0; k < H; k++) {
            float xk = x[k], hk = hp[k];
            gir += xk * wr[k];
            giz += xk * wz[k];
            gin += xk * wn[k];
            ghr += hk * vr[k];
            ghz += hk * vz[k];
            ghn += hk * vn[k];
        }
        float r = sigmoidf_(gir + ghr);
        float z = sigmoidf_(giz + ghz);
        float nn = tanhf_(gin + r * ghn);
        float hprev = hrow[j];  // L1 hit; not yet overwritten at index j
        float ho = (1.0f - z) * nn + z * hprev;
        hrow[j] = ho;
        a += ho * sWg[j];
        b += ho * sWg[H + j];
    }
    a_gate[n] = a;
    b_gate[n] = b;
}

// ---------------------------------------------------------------------------
// Final predictor: out[e] = pa[src] + pb[dst] + b_pred
__global__ __launch_bounds__(256) void predict_kernel(
    const int* __restrict__ src, const int* __restrict__ dst,
    const float* __restrict__ pa, const float* __restrict__ pb,
    const float* __restrict__ b_pred, float* __restrict__ out, int E)
{
    int e = blockIdx.x * 256 + threadIdx.x;
    if (e >= E) return;
    out[e] = pa[src[e]] + pb[dst[e]] + b_pred[0];
}

// ---------------------------------------------------------------------------
extern "C" void kernel_launch(void* const* d_in, const int* in_sizes, int n_in,
                              void* d_out, int out_size, void* d_ws, size_t ws_size,
                              hipStream_t stream) {
    const float* features = (const float*)d_in[0];
    const int*   src      = (const int*)d_in[1];
    const int*   dst      = (const int*)d_in[2];
    const float* W_in     = (const float*)d_in[3];
    const float* b_in     = (const float*)d_in[4];
    const float* W_edge   = (const float*)d_in[5];
    const float* b_edge   = (const float*)d_in[6];
    const float* Wih      = (const float*)d_in[7];
    const float* Whh      = (const float*)d_in[8];
    const float* bih      = (const float*)d_in[9];
    const float* bhh      = (const float*)d_in[10];
    const float* W_pred   = (const float*)d_in[11];
    const float* b_pred   = (const float*)d_in[12];
    float* out = (float*)d_out;

    int N = in_sizes[0] / 16;
    int E = in_sizes[1];
    int L = in_sizes[7] / (H3 * H);

    // workspace layout
    float* h      = (float*)d_ws;             // N*64
    float* h_new  = h + (size_t)N * H;        // N*64
    float* a_gate = h_new + (size_t)N * H;    // N
    float* b_gate = a_gate + N;               // N
    int*   deg    = (int*)(b_gate + N);       // N
    int*   offsets  = deg + N;                // N+1
    int*   counters = offsets + N + 1;        // N
    int*   csr_src  = counters + N;           // E

    int nb_nodes = (N + 255) / 256;
    int nb_edges = (E + 255) / 256;
    int nb_agg   = (N + 3) / 4;

    // CSR build
    hipMemsetAsync(deg, 0, (size_t)N * sizeof(int), stream);
    input_gates_kernel<<<nb_nodes, 256, 0, stream>>>(
        features, W_in, b_in, W_edge, h, a_gate, b_gate, N);
    hist_kernel<<<nb_edges, 256, 0, stream>>>(dst, deg, E);
    scan_kernel<<<1, 1024, 0, stream>>>(deg, offsets, counters, N, E);
    scatter_kernel<<<nb_edges, 256, 0, stream>>>(src, dst, counters, csr_src, E);

    for (int l = 0; l < L; l++) {
        aggregate_kernel<<<nb_agg, 256, 0, stream>>>(
            h, a_gate, b_gate, offsets, csr_src, b_edge, h_new, N);
        const float* Wg = (l < L - 1) ? W_edge : W_pred;
        gru_kernel<<<nb_nodes, 256, 0, stream>>>(
            h_new, h, Wih + (size_t)l * H3 * H, Whh + (size_t)l * H3 * H,
            bih + (size_t)l * H3, bhh + (size_t)l * H3, Wg, a_gate, b_gate, N);
    }

    predict_kernel<<<nb_edges, 256, 0, stream>>>(src, dst, a_gate, b_gate, b_pred, out, E);
}

// Round 2
// 513.058 us; speedup vs baseline: 2.2473x; 2.2473x over previous
//
#include <hip/hip_runtime.h>
#include <hip/hip_bf16.h>

#define H 64
#define H3 192

typedef __attribute__((ext_vector_type(8))) short short8;
typedef __attribute__((ext_vector_type(4))) float f32x4;

__device__ __forceinline__ float sigmoidf_(float x) {
    return 1.0f / (1.0f + __expf(-x));
}
__device__ __forceinline__ float tanhf_(float x) {
    float e = __expf(2.0f * x);
    return 1.0f - 2.0f / (e + 1.0f);
}
// f32 -> bf16 round-to-nearest-even (bit trick)
__device__ __forceinline__ unsigned short f2bf(float f) {
    unsigned u = __builtin_bit_cast(unsigned, f);
    u += 0x7FFFu + ((u >> 16) & 1u);
    return (unsigned short)(u >> 16);
}

// ---------------------------------------------------------------------------
// K1: h = features @ W_in + b_in; also a[n] = h.We[:64], b[n] = h.We[64:]
__global__ __launch_bounds__(256) void input_gates_kernel(
    const float* __restrict__ feat, const float* __restrict__ Win,
    const float* __restrict__ bin, const float* __restrict__ Wg,
    float* __restrict__ h, float* __restrict__ a_gate, float* __restrict__ b_gate,
    int N)
{
    __shared__ float sWin[16 * H];
    __shared__ float sbin[H];
    __shared__ float sWg[2 * H];
    int t = threadIdx.x;
    for (int i = t; i < 16 * H; i += 256) sWin[i] = Win[i];
    if (t < H) sbin[t] = bin[t];
    if (t < 2 * H) sWg[t] = Wg[t];
    __syncthreads();

    int n = blockIdx.x * 256 + t;
    if (n >= N) return;

    float f[16];
    const float4* fr = (const float4*)(feat + (size_t)n * 16);
#pragma unroll
    for (int i = 0; i < 4; i++) {
        float4 v = fr[i];
        f[4 * i + 0] = v.x; f[4 * i + 1] = v.y; f[4 * i + 2] = v.z; f[4 * i + 3] = v.w;
    }
    float a = 0.f, b = 0.f;
    float* hrow = h + (size_t)n * H;
    for (int j = 0; j < H; j++) {
        float hj = sbin[j];
#pragma unroll
        for (int k = 0; k < 16; k++) hj += f[k] * sWin[k * H + j];
        hrow[j] = hj;
        a += hj * sWg[j];
        b += hj * sWg[H + j];
    }
    a_gate[n] = a;
    b_gate[n] = b;
}

// ---------------------------------------------------------------------------
// weights f32 -> bf16 (both Wih and Whh stacks)
__global__ __launch_bounds__(256) void convert_w_kernel(
    const float* __restrict__ Wih, const float* __restrict__ Whh,
    unsigned short* __restrict__ out, int per)
{
    int i = blockIdx.x * 256 + threadIdx.x;
    if (i < per) out[i] = f2bf(Wih[i]);
    else if (i < 2 * per) out[i] = f2bf(Whh[i - per]);
}

// ---------------------------------------------------------------------------
// CSR build
__global__ __launch_bounds__(256) void hist_kernel(
    const int* __restrict__ dst, int* __restrict__ deg, int E)
{
    int e = blockIdx.x * 256 + threadIdx.x;
    if (e < E) atomicAdd(&deg[dst[e]], 1);
}

__global__ __launch_bounds__(1024) void scan_kernel(
    const int* __restrict__ deg, int* __restrict__ offsets,
    int* __restrict__ counters, int N, int E)
{
    __shared__ int sums[1024];
    int t = threadIdx.x;
    int chunk = (N + 1023) >> 10;
    int beg = t * chunk;
    int end = beg + chunk; if (end > N) end = N;
    if (beg > N) beg = N;
    int s = 0;
    for (int i = beg; i < end; i++) s += deg[i];
    sums[t] = s;
    __syncthreads();
    for (int off = 1; off < 1024; off <<= 1) {
        int v = (t >= off) ? sums[t - off] : 0;
        __syncthreads();
        sums[t] += v;
        __syncthreads();
    }
    int prefix = (t == 0) ? 0 : sums[t - 1];
    for (int i = beg; i < end; i++) {
        offsets[i] = prefix;
        counters[i] = prefix;
        prefix += deg[i];
    }
    if (t == 0) offsets[N] = E;
}

__global__ __launch_bounds__(256) void scatter_kernel(
    const int* __restrict__ src, const int* __restrict__ dst,
    int* __restrict__ counters, int* __restrict__ csr_src, int E)
{
    int e = blockIdx.x * 256 + threadIdx.x;
    if (e >= E) return;
    int d = dst[e];
    int pos = atomicAdd(&counters[d], 1);
    csr_src[pos] = src[e];
}

// ---------------------------------------------------------------------------
// Aggregate: h_new[v] = sum_{e: dst==v} sigmoid(a[src]+b[v]+be) * h[src]
// wave-per-node, lane = feature component; stores bf16 (GEMM operand dtype)
__global__ __launch_bounds__(256) void aggregate_kernel(
    const float* __restrict__ h, const float* __restrict__ a_gate,
    const float* __restrict__ b_gate, const int* __restrict__ offsets,
    const int* __restrict__ csr_src, const float* __restrict__ b_edge,
    unsigned short* __restrict__ hnew_bf, int N)
{
    int wid = threadIdx.x >> 6;
    int lane = threadIdx.x & 63;
    int v = blockIdx.x * 4 + wid;
    if (v >= N) return;

    int beg = offsets[v];
    int end = offsets[v + 1];
    float bv = b_gate[v] + b_edge[0];
    float acc = 0.f;

    for (int cs = beg; cs < end; cs += 64) {
        int m = end - cs; if (m > 64) m = 64;
        int u = 0; float w = 0.f;
        if (lane < m) {
            u = csr_src[cs + lane];
            w = sigmoidf_(a_gate[u] + bv);
        }
        for (int j = 0; j < m; j++) {
            int uj = __shfl(u, j);
            float wj = __shfl(w, j);
            acc += wj * h[(size_t)uj * H + lane];
        }
    }
    hnew_bf[(size_t)v * H + lane] = f2bf(acc);
}

// ---------------------------------------------------------------------------
// Fused GRU via MFMA bf16. Wave computes 16 nodes:
//   gi = x @ Wih^T, gh = h @ Whh^T  (12 j-tiles each, K=64 -> 2 mfma/tile)
// Fragment layout (16x16x32): A lane l holds row=l&15, k=(l>>4)*8+i (16B contig)
// Weights [192][64] row-major == B^T row-major -> same fragment mapping.
// C/D: col(j)=lane&15, row(node)=(lane>>4)*4+reg   [measured: m89]
__global__ __launch_bounds__(256) void gru_mfma_kernel(
    const unsigned short* __restrict__ x_bf,   // [N][64] bf16 (h_new)
    float* __restrict__ h,                     // [N][64] f32, in-place
    const unsigned short* __restrict__ wih_bf, // [192][64] bf16
    const unsigned short* __restrict__ whh_bf, // [192][64] bf16
    const float* __restrict__ bih, const float* __restrict__ bhh,
    const float* __restrict__ Wg,
    float* __restrict__ a_gate, float* __restrict__ b_gate, int N)
{
    int lane = threadIdx.x & 63;
    int wv = threadIdx.x >> 6;
    int c = lane & 15;      // j within tile / node-row for A
    int g = lane >> 4;      // k-group 0..3
    int nbase = blockIdx.x * 64 + wv * 16;
    if (nbase >= N) return;

    int nrow = nbase + c;
    int nclamp = nrow < N ? nrow : (N - 1);

    // A fragments
    short8 ax[2], ah[2];
#pragma unroll
    for (int ch = 0; ch < 2; ch++) {
        ax[ch] = *(const short8*)(x_bf + (size_t)nclamp * H + ch * 32 + g * 8);
        const float4* ph = (const float4*)(h + (size_t)nclamp * H + ch * 32 + g * 8);
        float4 h0 = ph[0], h1 = ph[1];
        short8 t;
        t[0] = (short)f2bf(h0.x); t[1] = (short)f2bf(h0.y);
        t[2] = (short)f2bf(h0.z); t[3] = (short)f2bf(h0.w);
        t[4] = (short)f2bf(h1.x); t[5] = (short)f2bf(h1.y);
        t[6] = (short)f2bf(h1.z); t[7] = (short)f2bf(h1.w);
        ah[ch] = t;
    }

    f32x4 gi[12], gh[12];
#pragma unroll
    for (int jb = 0; jb < 12; jb++) {
        gi[jb] = (f32x4){0.f, 0.f, 0.f, 0.f};
        gh[jb] = (f32x4){0.f, 0.f, 0.f, 0.f};
    }

#pragma unroll
    for (int jb = 0; jb < 12; jb++) {
        const unsigned short* wi = wih_bf + (size_t)(jb * 16 + c) * H + g * 8;
        const unsigned short* wh = whh_bf + (size_t)(jb * 16 + c) * H + g * 8;
        short8 wi0 = *(const short8*)(wi);
        short8 wi1 = *(const short8*)(wi + 32);
        short8 wh0 = *(const short8*)(wh);
        short8 wh1 = *(const short8*)(wh + 32);
        gi[jb] = __builtin_amdgcn_mfma_f32_16x16x32_bf16(ax[0], wi0, gi[jb], 0, 0, 0);
        gi[jb] = __builtin_amdgcn_mfma_f32_16x16x32_bf16(ax[1], wi1, gi[jb], 0, 0, 0);
        gh[jb] = __builtin_amdgcn_mfma_f32_16x16x32_bf16(ah[0], wh0, gh[jb], 0, 0, 0);
        gh[jb] = __builtin_amdgcn_mfma_f32_16x16x32_bf16(ah[1], wh1, gh[jb], 0, 0, 0);
    }

    // gates + in-place h update + next-stage per-node gate dots
    float pa[4] = {0.f, 0.f, 0.f, 0.f};
    float pb[4] = {0.f, 0.f, 0.f, 0.f};
#pragma unroll
    for (int jb = 0; jb < 4; jb++) {
        int j = jb * 16 + c;
        float br = bih[j] + bhh[j];
        float bz = bih[H + j] + bhh[H + j];
        float bin_ = bih[2 * H + j];
        float bhn_ = bhh[2 * H + j];
        float wga = Wg[j], wgb = Wg[H + j];
#pragma unroll
        for (int q = 0; q < 4; q++) {
            int node = nbase + g * 4 + q;
            float r = sigmoidf_(gi[jb][q] + gh[jb][q] + br);
            float z = sigmoidf_(gi[jb + 4][q] + gh[jb + 4][q] + bz);
            float nn = tanhf_(gi[jb + 8][q] + bin_ + r * (gh[jb + 8][q] + bhn_));
            size_t idx = (size_t)node * H + j;
            float hp = h[idx];
            float ho = (1.0f - z) * nn + z * hp;
            h[idx] = ho;
            pa[q] += ho * wga;
            pb[q] += ho * wgb;
        }
    }
    // reduce over the 16 lanes of each k-group (sum over j-columns)
#pragma unroll
    for (int m = 1; m < 16; m <<= 1) {
#pragma unroll
        for (int q = 0; q < 4; q++) {
            pa[q] += __shfl_xor(pa[q], m);
            pb[q] += __shfl_xor(pb[q], m);
        }
    }
    if (c == 0) {
#pragma unroll
        for (int q = 0; q < 4; q++) {
            int node = nbase + g * 4 + q;
            a_gate[node] = pa[q];
            b_gate[node] = pb[q];
        }
    }
}

// ---------------------------------------------------------------------------
// Final predictor: out[e] = pa[src] + pb[dst] + b_pred
__global__ __launch_bounds__(256) void predict_kernel(
    const int* __restrict__ src, const int* __restrict__ dst,
    const float* __restrict__ pa, const float* __restrict__ pb,
    const float* __restrict__ b_pred, float* __restrict__ out, int E)
{
    int e = blockIdx.x * 256 + threadIdx.x;
    if (e >= E) return;
    out[e] = pa[src[e]] + pb[dst[e]] + b_pred[0];
}

// ---------------------------------------------------------------------------
extern "C" void kernel_launch(void* const* d_in, const int* in_sizes, int n_in,
                              void* d_out, int out_size, void* d_ws, size_t ws_size,
                              hipStream_t stream) {
    const float* features = (const float*)d_in[0];
    const int*   src      = (const int*)d_in[1];
    const int*   dst      = (const int*)d_in[2];
    const float* W_in     = (const float*)d_in[3];
    const float* b_in     = (const float*)d_in[4];
    const float* W_edge   = (const float*)d_in[5];
    const float* b_edge   = (const float*)d_in[6];
    const float* Wih      = (const float*)d_in[7];
    const float* Whh      = (const float*)d_in[8];
    const float* bih      = (const float*)d_in[9];
    const float* bhh      = (const float*)d_in[10];
    const float* W_pred   = (const float*)d_in[11];
    const float* b_pred   = (const float*)d_in[12];
    float* out = (float*)d_out;

    int N = in_sizes[0] / 16;
    int E = in_sizes[1];
    int L = in_sizes[7] / (H3 * H);
    int per = L * H3 * H;  // elements per weight stack

    // workspace layout (16B-aligned segments)
    float* h = (float*)d_ws;                                   // N*64 f32
    unsigned short* hnew_bf = (unsigned short*)(h + (size_t)N * H);  // N*64 bf16
    unsigned short* w_bf = hnew_bf + (size_t)N * H;            // 2*per bf16
    float* a_gate = (float*)(w_bf + 2 * per);                  // N
    float* b_gate = a_gate + N;                                // N
    int* deg      = (int*)(b_gate + N);                        // N
    int* offsets  = deg + N;                                   // N+1
    int* counters = offsets + N + 1;                           // N
    int* csr_src  = counters + N;                              // E

    int nb_nodes = (N + 255) / 256;
    int nb_edges = (E + 255) / 256;
    int nb_agg   = (N + 3) / 4;
    int nb_gru   = (N + 63) / 64;
    int nb_conv  = (2 * per + 255) / 256;

    hipMemsetAsync(deg, 0, (size_t)N * sizeof(int), stream);
    input_gates_kernel<<<nb_nodes, 256, 0, stream>>>(
        features, W_in, b_in, W_edge, h, a_gate, b_gate, N);
    convert_w_kernel<<<nb_conv, 256, 0, stream>>>(Wih, Whh, w_bf, per);
    hist_kernel<<<nb_edges, 256, 0, stream>>>(dst, deg, E);
    scan_kernel<<<1, 1024, 0, stream>>>(deg, offsets, counters, N, E);
    scatter_kernel<<<nb_edges, 256, 0, stream>>>(src, dst, counters, csr_src, E);

    for (int l = 0; l < L; l++) {
        aggregate_kernel<<<nb_agg, 256, 0, stream>>>(
            h, a_gate, b_gate, offsets, csr_src, b_edge, hnew_bf, N);
        const float* Wg = (l < L - 1) ? W_edge : W_pred;
        gru_mfma_kernel<<<nb_gru, 256, 0, stream>>>(
            hnew_bf, h,
            w_bf + (size_t)l * H3 * H,            // Wih layer l
            w_bf + (size_t)per + (size_t)l * H3 * H,  // Whh layer l
            bih + (size_t)l * H3, bhh + (size_t)l * H3,
            Wg, a_gate, b_gate, N);
    }

    predict_kernel<<<nb_edges, 256, 0, stream>>>(src, dst, a_gate, b_gate, b_pred, out, E);
}

// Round 3
// 422.542 us; speedup vs baseline: 2.7287x; 1.2142x over previous
//
#include <hip/hip_runtime.h>
#include <hip/hip_bf16.h>

#define H 64
#define H3 192

typedef __attribute__((ext_vector_type(8))) short short8;
typedef __attribute__((ext_vector_type(4))) float f32x4;

__device__ __forceinline__ float sigmoidf_(float x) {
    return 1.0f / (1.0f + __expf(-x));
}
__device__ __forceinline__ float tanhf_(float x) {
    float e = __expf(2.0f * x);
    return 1.0f - 2.0f / (e + 1.0f);
}
// f32 -> bf16 round-to-nearest-even (bit trick)
__device__ __forceinline__ unsigned short f2bf(float f) {
    unsigned u = __builtin_bit_cast(unsigned, f);
    u += 0x7FFFu + ((u >> 16) & 1u);
    return (unsigned short)(u >> 16);
}

// ---------------------------------------------------------------------------
// K1: h = features @ W_in + b_in; also a[n] = h.We[:64], b[n] = h.We[64:]
__global__ __launch_bounds__(256) void input_gates_kernel(
    const float* __restrict__ feat, const float* __restrict__ Win,
    const float* __restrict__ bin, const float* __restrict__ Wg,
    float* __restrict__ h, float* __restrict__ a_gate, float* __restrict__ b_gate,
    int N)
{
    __shared__ float sWin[16 * H];
    __shared__ float sbin[H];
    __shared__ float sWg[2 * H];
    int t = threadIdx.x;
    for (int i = t; i < 16 * H; i += 256) sWin[i] = Win[i];
    if (t < H) sbin[t] = bin[t];
    if (t < 2 * H) sWg[t] = Wg[t];
    __syncthreads();

    int n = blockIdx.x * 256 + t;
    if (n >= N) return;

    float f[16];
    const float4* fr = (const float4*)(feat + (size_t)n * 16);
#pragma unroll
    for (int i = 0; i < 4; i++) {
        float4 v = fr[i];
        f[4 * i + 0] = v.x; f[4 * i + 1] = v.y; f[4 * i + 2] = v.z; f[4 * i + 3] = v.w;
    }
    float a = 0.f, b = 0.f;
    float* hrow = h + (size_t)n * H;
    for (int j = 0; j < H; j++) {
        float hj = sbin[j];
#pragma unroll
        for (int k = 0; k < 16; k++) hj += f[k] * sWin[k * H + j];
        hrow[j] = hj;
        a += hj * sWg[j];
        b += hj * sWg[H + j];
    }
    a_gate[n] = a;
    b_gate[n] = b;
}

// ---------------------------------------------------------------------------
// weights f32 -> bf16 (both Wih and Whh stacks)
__global__ __launch_bounds__(256) void convert_w_kernel(
    const float* __restrict__ Wih, const float* __restrict__ Whh,
    unsigned short* __restrict__ out, int per)
{
    int i = blockIdx.x * 256 + threadIdx.x;
    if (i < per) out[i] = f2bf(Wih[i]);
    else if (i < 2 * per) out[i] = f2bf(Whh[i - per]);
}

// ---------------------------------------------------------------------------
// CSR build
__global__ __launch_bounds__(256) void hist_kernel(
    const int* __restrict__ dst, int* __restrict__ deg, int E)
{
    int e = blockIdx.x * 256 + threadIdx.x;
    if (e < E) atomicAdd(&deg[dst[e]], 1);
}

// 3-pass multi-block exclusive scan of deg[N] -> offsets/counters
__global__ __launch_bounds__(256) void scan_pass1(
    const int* __restrict__ deg, int* __restrict__ locals,
    int* __restrict__ bsum, int N)
{
    int t = threadIdx.x;
    int i = blockIdx.x * 256 + t;
    int v = (i < N) ? deg[i] : 0;
    int lane = t & 63, w = t >> 6;
    int s = v;
#pragma unroll
    for (int off = 1; off < 64; off <<= 1) {
        int u = __shfl_up(s, off);
        if (lane >= off) s += u;
    }
    __shared__ int wsum[4];
    if (lane == 63) wsum[w] = s;
    __syncthreads();
    int add = 0;
    for (int k = 0; k < w; k++) add += wsum[k];
    if (i < N) locals[i] = s + add - v;   // block-local exclusive prefix
    if (t == 255) bsum[blockIdx.x] = s + add;  // block total
}

__global__ __launch_bounds__(1024) void scan_pass2(
    const int* __restrict__ bsum, int* __restrict__ carry, int nb)
{
    __shared__ int sums[1024];
    int t = threadIdx.x;
    int chunk = (nb + 1023) >> 10;
    int beg = t * chunk;
    int end = beg + chunk; if (end > nb) end = nb;
    if (beg > nb) beg = nb;
    int s = 0;
    for (int i = beg; i < end; i++) s += bsum[i];
    sums[t] = s;
    __syncthreads();
    for (int off = 1; off < 1024; off <<= 1) {
        int v = (t >= off) ? sums[t - off] : 0;
        __syncthreads();
        sums[t] += v;
        __syncthreads();
    }
    int prefix = (t == 0) ? 0 : sums[t - 1];
    for (int i = beg; i < end; i++) { carry[i] = prefix; prefix += bsum[i]; }
}

__global__ __launch_bounds__(256) void scan_pass3(
    const int* __restrict__ locals, const int* __restrict__ carry,
    int* __restrict__ offsets, int* __restrict__ counters, int N, int E)
{
    int i = blockIdx.x * 256 + threadIdx.x;
    if (i < N) {
        int o = locals[i] + carry[blockIdx.x];
        offsets[i] = o;
        counters[i] = o;
    } else if (i == N) {
        offsets[N] = E;
    }
}

__global__ __launch_bounds__(256) void scatter_kernel(
    const int* __restrict__ src, const int* __restrict__ dst,
    int* __restrict__ counters, int* __restrict__ csr_src, int E)
{
    int e = blockIdx.x * 256 + threadIdx.x;
    if (e >= E) return;
    int d = dst[e];
    int pos = atomicAdd(&counters[d], 1);
    csr_src[pos] = src[e];
}

// ---------------------------------------------------------------------------
// Aggregate: h_new[v] = sum_{e: dst==v} sigmoid(a[src]+b[v]+be) * h[src]
// wave-per-node, lane = feature component; stores bf16 (GEMM operand dtype)
__global__ __launch_bounds__(256) void aggregate_kernel(
    const float* __restrict__ h, const float* __restrict__ a_gate,
    const float* __restrict__ b_gate, const int* __restrict__ offsets,
    const int* __restrict__ csr_src, const float* __restrict__ b_edge,
    unsigned short* __restrict__ hnew_bf, int N)
{
    int wid = threadIdx.x >> 6;
    int lane = threadIdx.x & 63;
    int v = blockIdx.x * 4 + wid;
    if (v >= N) return;

    int beg = offsets[v];
    int end = offsets[v + 1];
    float bv = b_gate[v] + b_edge[0];
    float acc = 0.f;

    for (int cs = beg; cs < end; cs += 64) {
        int m = end - cs; if (m > 64) m = 64;
        int u = 0; float w = 0.f;
        if (lane < m) {
            u = csr_src[cs + lane];
            w = sigmoidf_(a_gate[u] + bv);
        }
        for (int j = 0; j < m; j++) {
            int uj = __shfl(u, j);
            float wj = __shfl(w, j);
            acc += wj * h[(size_t)uj * H + lane];
        }
    }
    hnew_bf[(size_t)v * H + lane] = f2bf(acc);
}

// ---------------------------------------------------------------------------
// Fused GRU via MFMA bf16. Wave computes 16 nodes.
// C/D: col(j)=lane&15, row(node)=(lane>>4)*4+reg   [measured: m89]
__global__ __launch_bounds__(256) void gru_mfma_kernel(
    const unsigned short* __restrict__ x_bf,   // [N][64] bf16 (h_new)
    float* __restrict__ h,                     // [N][64] f32, in-place
    const unsigned short* __restrict__ wih_bf, // [192][64] bf16
    const unsigned short* __restrict__ whh_bf, // [192][64] bf16
    const float* __restrict__ bih, const float* __restrict__ bhh,
    const float* __restrict__ Wg,
    float* __restrict__ a_gate, float* __restrict__ b_gate, int N)
{
    int lane = threadIdx.x & 63;
    int wv = threadIdx.x >> 6;
    int c = lane & 15;      // j within tile / node-row for A
    int g = lane >> 4;      // k-group 0..3
    int nbase = blockIdx.x * 64 + wv * 16;
    if (nbase >= N) return;

    int nrow = nbase + c;
    int nclamp = nrow < N ? nrow : (N - 1);

    // A fragments
    short8 ax[2], ah[2];
#pragma unroll
    for (int ch = 0; ch < 2; ch++) {
        ax[ch] = *(const short8*)(x_bf + (size_t)nclamp * H + ch * 32 + g * 8);
        const float4* ph = (const float4*)(h + (size_t)nclamp * H + ch * 32 + g * 8);
        float4 h0 = ph[0], h1 = ph[1];
        short8 t;
        t[0] = (short)f2bf(h0.x); t[1] = (short)f2bf(h0.y);
        t[2] = (short)f2bf(h0.z); t[3] = (short)f2bf(h0.w);
        t[4] = (short)f2bf(h1.x); t[5] = (short)f2bf(h1.y);
        t[6] = (short)f2bf(h1.z); t[7] = (short)f2bf(h1.w);
        ah[ch] = t;
    }

    f32x4 gi[12], gh[12];
#pragma unroll
    for (int jb = 0; jb < 12; jb++) {
        gi[jb] = (f32x4){0.f, 0.f, 0.f, 0.f};
        gh[jb] = (f32x4){0.f, 0.f, 0.f, 0.f};
    }

#pragma unroll
    for (int jb = 0; jb < 12; jb++) {
        const unsigned short* wi = wih_bf + (size_t)(jb * 16 + c) * H + g * 8;
        const unsigned short* wh = whh_bf + (size_t)(jb * 16 + c) * H + g * 8;
        short8 wi0 = *(const short8*)(wi);
        short8 wi1 = *(const short8*)(wi + 32);
        short8 wh0 = *(const short8*)(wh);
        short8 wh1 = *(const short8*)(wh + 32);
        gi[jb] = __builtin_amdgcn_mfma_f32_16x16x32_bf16(ax[0], wi0, gi[jb], 0, 0, 0);
        gi[jb] = __builtin_amdgcn_mfma_f32_16x16x32_bf16(ax[1], wi1, gi[jb], 0, 0, 0);
        gh[jb] = __builtin_amdgcn_mfma_f32_16x16x32_bf16(ah[0], wh0, gh[jb], 0, 0, 0);
        gh[jb] = __builtin_amdgcn_mfma_f32_16x16x32_bf16(ah[1], wh1, gh[jb], 0, 0, 0);
    }

    // gates + in-place h update + next-stage per-node gate dots
    float pa[4] = {0.f, 0.f, 0.f, 0.f};
    float pb[4] = {0.f, 0.f, 0.f, 0.f};
#pragma unroll
    for (int jb = 0; jb < 4; jb++) {
        int j = jb * 16 + c;
        float br = bih[j] + bhh[j];
        float bz = bih[H + j] + bhh[H + j];
        float bin_ = bih[2 * H + j];
        float bhn_ = bhh[2 * H + j];
        float wga = Wg[j], wgb = Wg[H + j];
#pragma unroll
        for (int q = 0; q < 4; q++) {
            int node = nbase + g * 4 + q;
            float r = sigmoidf_(gi[jb][q] + gh[jb][q] + br);
            float z = sigmoidf_(gi[jb + 4][q] + gh[jb + 4][q] + bz);
            float nn = tanhf_(gi[jb + 8][q] + bin_ + r * (gh[jb + 8][q] + bhn_));
            size_t idx = (size_t)node * H + j;
            float hp = h[idx];
            float ho = (1.0f - z) * nn + z * hp;
            h[idx] = ho;
            pa[q] += ho * wga;
            pb[q] += ho * wgb;
        }
    }
    // reduce over the 16 lanes of each k-group (sum over j-columns)
#pragma unroll
    for (int m = 1; m < 16; m <<= 1) {
#pragma unroll
        for (int q = 0; q < 4; q++) {
            pa[q] += __shfl_xor(pa[q], m);
            pb[q] += __shfl_xor(pb[q], m);
        }
    }
    if (c == 0) {
#pragma unroll
        for (int q = 0; q < 4; q++) {
            int node = nbase + g * 4 + q;
            a_gate[node] = pa[q];
            b_gate[node] = pb[q];
        }
    }
}

// ---------------------------------------------------------------------------
// Final predictor: out[e] = pa[src] + pb[dst] + b_pred
__global__ __launch_bounds__(256) void predict_kernel(
    const int* __restrict__ src, const int* __restrict__ dst,
    const float* __restrict__ pa, const float* __restrict__ pb,
    const float* __restrict__ b_pred, float* __restrict__ out, int E)
{
    int e = blockIdx.x * 256 + threadIdx.x;
    if (e >= E) return;
    out[e] = pa[src[e]] + pb[dst[e]] + b_pred[0];
}

// ---------------------------------------------------------------------------
extern "C" void kernel_launch(void* const* d_in, const int* in_sizes, int n_in,
                              void* d_out, int out_size, void* d_ws, size_t ws_size,
                              hipStream_t stream) {
    const float* features = (const float*)d_in[0];
    const int*   src      = (const int*)d_in[1];
    const int*   dst      = (const int*)d_in[2];
    const float* W_in     = (const float*)d_in[3];
    const float* b_in     = (const float*)d_in[4];
    const float* W_edge   = (const float*)d_in[5];
    const float* b_edge   = (const float*)d_in[6];
    const float* Wih      = (const float*)d_in[7];
    const float* Whh      = (const float*)d_in[8];
    const float* bih      = (const float*)d_in[9];
    const float* bhh      = (const float*)d_in[10];
    const float* W_pred   = (const float*)d_in[11];
    const float* b_pred   = (const float*)d_in[12];
    float* out = (float*)d_out;

    int N = in_sizes[0] / 16;
    int E = in_sizes[1];
    int L = in_sizes[7] / (H3 * H);
    int per = L * H3 * H;  // elements per weight stack

    int nb_nodes = (N + 255) / 256;   // also the #blocks for scan pass1
    int nb_edges = (E + 255) / 256;
    int nb_agg   = (N + 3) / 4;
    int nb_gru   = (N + 63) / 64;
    int nb_conv  = (2 * per + 255) / 256;
    int nb_off   = (N + 1 + 255) / 256;

    // workspace layout (16B-aligned segments)
    float* h = (float*)d_ws;                                   // N*64 f32
    unsigned short* hnew_bf = (unsigned short*)(h + (size_t)N * H);  // N*64 bf16
    unsigned short* w_bf = hnew_bf + (size_t)N * H;            // 2*per bf16
    float* a_gate = (float*)(w_bf + 2 * per);                  // N
    float* b_gate = a_gate + N;                                // N
    int* deg      = (int*)(b_gate + N);                        // N
    int* offsets  = deg + N;                                   // N+1
    int* counters = offsets + N + 1;                           // N
    int* locals   = counters + N;                              // N
    int* bsum     = locals + N;                                // nb_nodes
    int* carry    = bsum + nb_nodes;                           // nb_nodes
    int* csr_src  = carry + nb_nodes;                          // E

    hipMemsetAsync(deg, 0, (size_t)N * sizeof(int), stream);
    input_gates_kernel<<<nb_nodes, 256, 0, stream>>>(
        features, W_in, b_in, W_edge, h, a_gate, b_gate, N);
    convert_w_kernel<<<nb_conv, 256, 0, stream>>>(Wih, Whh, w_bf, per);
    hist_kernel<<<nb_edges, 256, 0, stream>>>(dst, deg, E);
    scan_pass1<<<nb_nodes, 256, 0, stream>>>(deg, locals, bsum, N);
    scan_pass2<<<1, 1024, 0, stream>>>(bsum, carry, nb_nodes);
    scan_pass3<<<nb_off, 256, 0, stream>>>(locals, carry, offsets, counters, N, E);
    scatter_kernel<<<nb_edges, 256, 0, stream>>>(src, dst, counters, csr_src, E);

    for (int l = 0; l < L; l++) {
        aggregate_kernel<<<nb_agg, 256, 0, stream>>>(
            h, a_gate, b_gate, offsets, csr_src, b_edge, hnew_bf, N);
        const float* Wg = (l < L - 1) ? W_edge : W_pred;
        gru_mfma_kernel<<<nb_gru, 256, 0, stream>>>(
            hnew_bf, h,
            w_bf + (size_t)l * H3 * H,                 // Wih layer l
            w_bf + (size_t)per + (size_t)l * H3 * H,   // Whh layer l
            bih + (size_t)l * H3, bhh + (size_t)l * H3,
            Wg, a_gate, b_gate, N);
    }

    predict_kernel<<<nb_edges, 256, 0, stream>>>(src, dst, a_gate, b_gate, b_pred, out, E);
}

// Round 4
// 343.339 us; speedup vs baseline: 3.3582x; 1.2307x over previous
//
#include <hip/hip_runtime.h>
#include <hip/hip_bf16.h>

#define H 64
#define H3 192

typedef __attribute__((ext_vector_type(8))) short short8;
typedef __attribute__((ext_vector_type(4))) float f32x4;

__device__ __forceinline__ float sigmoidf_(float x) {
    return 1.0f / (1.0f + __expf(-x));
}
__device__ __forceinline__ float tanhf_(float x) {
    float e = __expf(2.0f * x);
    return 1.0f - 2.0f / (e + 1.0f);
}
// f32 -> bf16 round-to-nearest-even (bit trick)
__device__ __forceinline__ unsigned short f2bf(float f) {
    unsigned u = __builtin_bit_cast(unsigned, f);
    u += 0x7FFFu + ((u >> 16) & 1u);
    return (unsigned short)(u >> 16);
}

// ---------------------------------------------------------------------------
// K1: h = features @ W_in + b_in; also a[n] = h.We[:64], b[n] = h.We[64:]
__global__ __launch_bounds__(256) void input_gates_kernel(
    const float* __restrict__ feat, const float* __restrict__ Win,
    const float* __restrict__ bin, const float* __restrict__ Wg,
    float* __restrict__ h, float* __restrict__ a_gate, float* __restrict__ b_gate,
    int N)
{
    __shared__ float sWin[16 * H];
    __shared__ float sbin[H];
    __shared__ float sWg[2 * H];
    int t = threadIdx.x;
    for (int i = t; i < 16 * H; i += 256) sWin[i] = Win[i];
    if (t < H) sbin[t] = bin[t];
    if (t < 2 * H) sWg[t] = Wg[t];
    __syncthreads();

    int n = blockIdx.x * 256 + t;
    if (n >= N) return;

    float f[16];
    const float4* fr = (const float4*)(feat + (size_t)n * 16);
#pragma unroll
    for (int i = 0; i < 4; i++) {
        float4 v = fr[i];
        f[4 * i + 0] = v.x; f[4 * i + 1] = v.y; f[4 * i + 2] = v.z; f[4 * i + 3] = v.w;
    }
    float a = 0.f, b = 0.f;
    float* hrow = h + (size_t)n * H;
    for (int j = 0; j < H; j++) {
        float hj = sbin[j];
#pragma unroll
        for (int k = 0; k < 16; k++) hj += f[k] * sWin[k * H + j];
        hrow[j] = hj;
        a += hj * sWg[j];
        b += hj * sWg[H + j];
    }
    a_gate[n] = a;
    b_gate[n] = b;
}

// ---------------------------------------------------------------------------
// weights f32 -> bf16 (both Wih and Whh stacks)
__global__ __launch_bounds__(256) void convert_w_kernel(
    const float* __restrict__ Wih, const float* __restrict__ Whh,
    unsigned short* __restrict__ out, int per)
{
    int i = blockIdx.x * 256 + threadIdx.x;
    if (i < per) out[i] = f2bf(Wih[i]);
    else if (i < 2 * per) out[i] = f2bf(Whh[i - per]);
}

// ---------------------------------------------------------------------------
// CSR build
__global__ __launch_bounds__(256) void hist_kernel(
    const int* __restrict__ dst, int* __restrict__ deg, int E)
{
    int e = blockIdx.x * 256 + threadIdx.x;
    if (e < E) atomicAdd(&deg[dst[e]], 1);
}

// 3-pass multi-block exclusive scan of deg[N] -> offsets/counters
__global__ __launch_bounds__(256) void scan_pass1(
    const int* __restrict__ deg, int* __restrict__ locals,
    int* __restrict__ bsum, int N)
{
    int t = threadIdx.x;
    int i = blockIdx.x * 256 + t;
    int v = (i < N) ? deg[i] : 0;
    int lane = t & 63, w = t >> 6;
    int s = v;
#pragma unroll
    for (int off = 1; off < 64; off <<= 1) {
        int u = __shfl_up(s, off);
        if (lane >= off) s += u;
    }
    __shared__ int wsum[4];
    if (lane == 63) wsum[w] = s;
    __syncthreads();
    int add = 0;
    for (int k = 0; k < w; k++) add += wsum[k];
    if (i < N) locals[i] = s + add - v;   // block-local exclusive prefix
    if (t == 255) bsum[blockIdx.x] = s + add;  // block total
}

__global__ __launch_bounds__(1024) void scan_pass2(
    const int* __restrict__ bsum, int* __restrict__ carry, int nb)
{
    __shared__ int sums[1024];
    int t = threadIdx.x;
    int chunk = (nb + 1023) >> 10;
    int beg = t * chunk;
    int end = beg + chunk; if (end > nb) end = nb;
    if (beg > nb) beg = nb;
    int s = 0;
    for (int i = beg; i < end; i++) s += bsum[i];
    sums[t] = s;
    __syncthreads();
    for (int off = 1; off < 1024; off <<= 1) {
        int v = (t >= off) ? sums[t - off] : 0;
        __syncthreads();
        sums[t] += v;
        __syncthreads();
    }
    int prefix = (t == 0) ? 0 : sums[t - 1];
    for (int i = beg; i < end; i++) { carry[i] = prefix; prefix += bsum[i]; }
}

__global__ __launch_bounds__(256) void scan_pass3(
    const int* __restrict__ locals, const int* __restrict__ carry,
    int* __restrict__ offsets, int* __restrict__ counters, int N, int E)
{
    int i = blockIdx.x * 256 + threadIdx.x;
    if (i < N) {
        int o = locals[i] + carry[blockIdx.x];
        offsets[i] = o;
        counters[i] = o;
    } else if (i == N) {
        offsets[N] = E;
    }
}

__global__ __launch_bounds__(256) void scatter_kernel(
    const int* __restrict__ src, const int* __restrict__ dst,
    int* __restrict__ counters, int* __restrict__ csr_src, int E)
{
    int e = blockIdx.x * 256 + threadIdx.x;
    if (e >= E) return;
    int d = dst[e];
    int pos = atomicAdd(&counters[d], 1);
    csr_src[pos] = src[e];
}

// ---------------------------------------------------------------------------
// Aggregate: h_new[v] = sum_{e: dst==v} sigmoid(a[src]+b[v]+be) * h[src]
// wave-per-node. Phase 1: 64 lanes preload (u,w) in parallel.
// Phase 2: 4x16 lanes, each 16-lane group reads one full h-row (float4/lane).
__global__ __launch_bounds__(256) void aggregate_kernel(
    const float* __restrict__ h, const float* __restrict__ a_gate,
    const float* __restrict__ b_gate, const int* __restrict__ offsets,
    const int* __restrict__ csr_src, const float* __restrict__ b_edge,
    unsigned short* __restrict__ hnew_bf, int N)
{
    int wid = threadIdx.x >> 6;
    int lane = threadIdx.x & 63;
    int sub = lane >> 4;     // edge slot 0..3
    int cg  = lane & 15;     // component group (4 floats)
    int v = blockIdx.x * 4 + wid;
    if (v >= N) return;

    int beg = offsets[v];
    int end = offsets[v + 1];
    float bv = b_gate[v] + b_edge[0];
    float4 acc = {0.f, 0.f, 0.f, 0.f};

    for (int cs = beg; cs < end; cs += 64) {
        int m = end - cs; if (m > 64) m = 64;
        int u = 0; float w = 0.f;
        if (lane < m) {
            u = csr_src[cs + lane];
            w = sigmoidf_(a_gate[u] + bv);
        }
        for (int j = 0; j < m; j += 4) {
            int e = j + sub;                 // edge within chunk for this group
            int uj = __shfl(u, e & 63);      // lanes with e>=m broadcast u=0 (safe)
            float wj = __shfl(w, e & 63);
            if (e >= m) wj = 0.f;
            float4 hv = *(const float4*)(h + (size_t)uj * H + cg * 4);
            acc.x += wj * hv.x; acc.y += wj * hv.y;
            acc.z += wj * hv.z; acc.w += wj * hv.w;
        }
    }
    // reduce across the 4 sub-groups (lane bits 4,5)
#pragma unroll
    for (int m = 16; m < 64; m <<= 1) {
        acc.x += __shfl_xor(acc.x, m);
        acc.y += __shfl_xor(acc.y, m);
        acc.z += __shfl_xor(acc.z, m);
        acc.w += __shfl_xor(acc.w, m);
    }
    if (sub == 0) {
        ushort4 o;
        o.x = f2bf(acc.x); o.y = f2bf(acc.y);
        o.z = f2bf(acc.z); o.w = f2bf(acc.w);
        *(ushort4*)(hnew_bf + (size_t)v * H + cg * 4) = o;
    }
}

// ---------------------------------------------------------------------------
// Fused GRU via MFMA bf16. Wave computes 16 nodes.
// C/D: col(j)=lane&15, row(node)=(lane>>4)*4+reg   [measured: m89]
__global__ __launch_bounds__(256) void gru_mfma_kernel(
    const unsigned short* __restrict__ x_bf,   // [N][64] bf16 (h_new)
    float* __restrict__ h,                     // [N][64] f32, in-place
    const unsigned short* __restrict__ wih_bf, // [192][64] bf16
    const unsigned short* __restrict__ whh_bf, // [192][64] bf16
    const float* __restrict__ bih, const float* __restrict__ bhh,
    const float* __restrict__ Wg,
    float* __restrict__ a_gate, float* __restrict__ b_gate, int N)
{
    int lane = threadIdx.x & 63;
    int wv = threadIdx.x >> 6;
    int c = lane & 15;      // j within tile / node-row for A
    int g = lane >> 4;      // k-group 0..3
    int nbase = blockIdx.x * 64 + wv * 16;
    if (nbase >= N) return;

    int nrow = nbase + c;
    int nclamp = nrow < N ? nrow : (N - 1);

    // A fragments
    short8 ax[2], ah[2];
#pragma unroll
    for (int ch = 0; ch < 2; ch++) {
        ax[ch] = *(const short8*)(x_bf + (size_t)nclamp * H + ch * 32 + g * 8);
        const float4* ph = (const float4*)(h + (size_t)nclamp * H + ch * 32 + g * 8);
        float4 h0 = ph[0], h1 = ph[1];
        short8 t;
        t[0] = (short)f2bf(h0.x); t[1] = (short)f2bf(h0.y);
        t[2] = (short)f2bf(h0.z); t[3] = (short)f2bf(h0.w);
        t[4] = (short)f2bf(h1.x); t[5] = (short)f2bf(h1.y);
        t[6] = (short)f2bf(h1.z); t[7] = (short)f2bf(h1.w);
        ah[ch] = t;
    }

    f32x4 gi[12], gh[12];
#pragma unroll
    for (int jb = 0; jb < 12; jb++) {
        gi[jb] = (f32x4){0.f, 0.f, 0.f, 0.f};
        gh[jb] = (f32x4){0.f, 0.f, 0.f, 0.f};
    }

#pragma unroll
    for (int jb = 0; jb < 12; jb++) {
        const unsigned short* wi = wih_bf + (size_t)(jb * 16 + c) * H + g * 8;
        const unsigned short* wh = whh_bf + (size_t)(jb * 16 + c) * H + g * 8;
        short8 wi0 = *(const short8*)(wi);
        short8 wi1 = *(const short8*)(wi + 32);
        short8 wh0 = *(const short8*)(wh);
        short8 wh1 = *(const short8*)(wh + 32);
        gi[jb] = __builtin_amdgcn_mfma_f32_16x16x32_bf16(ax[0], wi0, gi[jb], 0, 0, 0);
        gi[jb] = __builtin_amdgcn_mfma_f32_16x16x32_bf16(ax[1], wi1, gi[jb], 0, 0, 0);
        gh[jb] = __builtin_amdgcn_mfma_f32_16x16x32_bf16(ah[0], wh0, gh[jb], 0, 0, 0);
        gh[jb] = __builtin_amdgcn_mfma_f32_16x16x32_bf16(ah[1], wh1, gh[jb], 0, 0, 0);
    }

    // gates + in-place h update + next-stage per-node gate dots
    float pa[4] = {0.f, 0.f, 0.f, 0.f};
    float pb[4] = {0.f, 0.f, 0.f, 0.f};
#pragma unroll
    for (int jb = 0; jb < 4; jb++) {
        int j = jb * 16 + c;
        float br = bih[j] + bhh[j];
        float bz = bih[H + j] + bhh[H + j];
        float bin_ = bih[2 * H + j];
        float bhn_ = bhh[2 * H + j];
        float wga = Wg[j], wgb = Wg[H + j];
#pragma unroll
        for (int q = 0; q < 4; q++) {
            int node = nbase + g * 4 + q;
            float r = sigmoidf_(gi[jb][q] + gh[jb][q] + br);
            float z = sigmoidf_(gi[jb + 4][q] + gh[jb + 4][q] + bz);
            float nn = tanhf_(gi[jb + 8][q] + bin_ + r * (gh[jb + 8][q] + bhn_));
            size_t idx = (size_t)node * H + j;
            float hp = h[idx];
            float ho = (1.0f - z) * nn + z * hp;
            h[idx] = ho;
            pa[q] += ho * wga;
            pb[q] += ho * wgb;
        }
    }
    // reduce over the 16 lanes of each k-group (sum over j-columns)
#pragma unroll
    for (int m = 1; m < 16; m <<= 1) {
#pragma unroll
        for (int q = 0; q < 4; q++) {
            pa[q] += __shfl_xor(pa[q], m);
            pb[q] += __shfl_xor(pb[q], m);
        }
    }
    if (c == 0) {
#pragma unroll
        for (int q = 0; q < 4; q++) {
            int node = nbase + g * 4 + q;
            a_gate[node] = pa[q];
            b_gate[node] = pb[q];
        }
    }
}

// ---------------------------------------------------------------------------
// Final predictor: out[e] = pa[src] + pb[dst] + b_pred
__global__ __launch_bounds__(256) void predict_kernel(
    const int* __restrict__ src, const int* __restrict__ dst,
    const float* __restrict__ pa, const float* __restrict__ pb,
    const float* __restrict__ b_pred, float* __restrict__ out, int E)
{
    int e = blockIdx.x * 256 + threadIdx.x;
    if (e >= E) return;
    out[e] = pa[src[e]] + pb[dst[e]] + b_pred[0];
}

// ---------------------------------------------------------------------------
extern "C" void kernel_launch(void* const* d_in, const int* in_sizes, int n_in,
                              void* d_out, int out_size, void* d_ws, size_t ws_size,
                              hipStream_t stream) {
    const float* features = (const float*)d_in[0];
    const int*   src      = (const int*)d_in[1];
    const int*   dst      = (const int*)d_in[2];
    const float* W_in     = (const float*)d_in[3];
    const float* b_in     = (const float*)d_in[4];
    const float* W_edge   = (const float*)d_in[5];
    const float* b_edge   = (const float*)d_in[6];
    const float* Wih      = (const float*)d_in[7];
    const float* Whh      = (const float*)d_in[8];
    const float* bih      = (const float*)d_in[9];
    const float* bhh      = (const float*)d_in[10];
    const float* W_pred   = (const float*)d_in[11];
    const float* b_pred   = (const float*)d_in[12];
    float* out = (float*)d_out;

    int N = in_sizes[0] / 16;
    int E = in_sizes[1];
    int L = in_sizes[7] / (H3 * H);
    int per = L * H3 * H;  // elements per weight stack

    int nb_nodes = (N + 255) / 256;   // also the #blocks for scan pass1
    int nb_edges = (E + 255) / 256;
    int nb_agg   = (N + 3) / 4;
    int nb_gru   = (N + 63) / 64;
    int nb_conv  = (2 * per + 255) / 256;
    int nb_off   = (N + 1 + 255) / 256;

    // workspace layout (16B-aligned segments)
    float* h = (float*)d_ws;                                   // N*64 f32
    unsigned short* hnew_bf = (unsigned short*)(h + (size_t)N * H);  // N*64 bf16
    unsigned short* w_bf = hnew_bf + (size_t)N * H;            // 2*per bf16
    float* a_gate = (float*)(w_bf + 2 * per);                  // N
    float* b_gate = a_gate + N;                                // N
    int* deg      = (int*)(b_gate + N);                        // N
    int* offsets  = deg + N;                                   // N+1
    int* counters = offsets + N + 1;                           // N
    int* locals   = counters + N;                              // N
    int* bsum     = locals + N;                                // nb_nodes
    int* carry    = bsum + nb_nodes;                           // nb_nodes
    int* csr_src  = carry + nb_nodes;                          // E

    hipMemsetAsync(deg, 0, (size_t)N * sizeof(int), stream);
    input_gates_kernel<<<nb_nodes, 256, 0, stream>>>(
        features, W_in, b_in, W_edge, h, a_gate, b_gate, N);
    convert_w_kernel<<<nb_conv, 256, 0, stream>>>(Wih, Whh, w_bf, per);
    hist_kernel<<<nb_edges, 256, 0, stream>>>(dst, deg, E);
    scan_pass1<<<nb_nodes, 256, 0, stream>>>(deg, locals, bsum, N);
    scan_pass2<<<1, 1024, 0, stream>>>(bsum, carry, nb_nodes);
    scan_pass3<<<nb_off, 256, 0, stream>>>(locals, carry, offsets, counters, N, E);
    scatter_kernel<<<nb_edges, 256, 0, stream>>>(src, dst, counters, csr_src, E);

    for (int l = 0; l < L; l++) {
        aggregate_kernel<<<nb_agg, 256, 0, stream>>>(
            h, a_gate, b_gate, offsets, csr_src, b_edge, hnew_bf, N);
        const float* Wg = (l < L - 1) ? W_edge : W_pred;
        gru_mfma_kernel<<<nb_gru, 256, 0, stream>>>(
            hnew_bf, h,
            w_bf + (size_t)l * H3 * H,                 // Wih layer l
            w_bf + (size_t)per + (size_t)l * H3 * H,   // Whh layer l
            bih + (size_t)l * H3, bhh + (size_t)l * H3,
            Wg, a_gate, b_gate, N);
    }

    predict_kernel<<<nb_edges, 256, 0, stream>>>(src, dst, a_gate, b_gate, b_pred, out, E);
}

// Round 5
// 282.937 us; speedup vs baseline: 4.0751x; 1.2135x over previous
//
#include <hip/hip_runtime.h>
#include <hip/hip_bf16.h>

#define H 64
#define H3 192
#define ITEMS 16   // edges per thread in bucket hist/scatter (4096/block)

typedef __attribute__((ext_vector_type(8))) short short8;
typedef __attribute__((ext_vector_type(4))) float f32x4;

__device__ __forceinline__ float sigmoidf_(float x) {
    return 1.0f / (1.0f + __expf(-x));
}
__device__ __forceinline__ float tanhf_(float x) {
    float e = __expf(2.0f * x);
    return 1.0f - 2.0f / (e + 1.0f);
}
// f32 -> bf16 round-to-nearest-even (bit trick)
__device__ __forceinline__ unsigned short f2bf(float f) {
    unsigned u = __builtin_bit_cast(unsigned, f);
    u += 0x7FFFu + ((u >> 16) & 1u);
    return (unsigned short)(u >> 16);
}

// ---------------------------------------------------------------------------
// K1: h = features @ W_in + b_in; also a[n] = h.We[:64], b[n] = h.We[64:]
__global__ __launch_bounds__(256) void input_gates_kernel(
    const float* __restrict__ feat, const float* __restrict__ Win,
    const float* __restrict__ bin, const float* __restrict__ Wg,
    float* __restrict__ h, float* __restrict__ a_gate, float* __restrict__ b_gate,
    int N)
{
    __shared__ float sWin[16 * H];
    __shared__ float sbin[H];
    __shared__ float sWg[2 * H];
    int t = threadIdx.x;
    for (int i = t; i < 16 * H; i += 256) sWin[i] = Win[i];
    if (t < H) sbin[t] = bin[t];
    if (t < 2 * H) sWg[t] = Wg[t];
    __syncthreads();

    int n = blockIdx.x * 256 + t;
    if (n >= N) return;

    float f[16];
    const float4* fr = (const float4*)(feat + (size_t)n * 16);
#pragma unroll
    for (int i = 0; i < 4; i++) {
        float4 v = fr[i];
        f[4 * i + 0] = v.x; f[4 * i + 1] = v.y; f[4 * i + 2] = v.z; f[4 * i + 3] = v.w;
    }
    float a = 0.f, b = 0.f;
    float* hrow = h + (size_t)n * H;
    for (int j = 0; j < H; j++) {
        float hj = sbin[j];
#pragma unroll
        for (int k = 0; k < 16; k++) hj += f[k] * sWin[k * H + j];
        hrow[j] = hj;
        a += hj * sWg[j];
        b += hj * sWg[H + j];
    }
    a_gate[n] = a;
    b_gate[n] = b;
}

// ---------------------------------------------------------------------------
// weights f32 -> bf16 (both Wih and Whh stacks)
__global__ __launch_bounds__(256) void convert_w_kernel(
    const float* __restrict__ Wih, const float* __restrict__ Whh,
    unsigned short* __restrict__ out, int per)
{
    int i = blockIdx.x * 256 + threadIdx.x;
    if (i < per) out[i] = f2bf(Wih[i]);
    else if (i < 2 * per) out[i] = f2bf(Whh[i - per]);
}

// ---------------------------------------------------------------------------
// CSR build via 2-level bucket sort. bucket = dst>>8 (contiguous dst range).
// Pass A: per-block LDS histogram of buckets -> bhist[bucket][block]
__global__ __launch_bounds__(256) void bucket_hist_kernel(
    const int* __restrict__ dst, int* __restrict__ bhist, int E, int nb_c)
{
    __shared__ int lh[256];
    int t = threadIdx.x;
    lh[t] = 0;
    __syncthreads();
    int base = blockIdx.x * (256 * ITEMS);
#pragma unroll
    for (int k = 0; k < ITEMS; k++) {
        int i = base + k * 256 + t;
        if (i < E) atomicAdd(&lh[dst[i] >> 8], 1);
    }
    __syncthreads();
    bhist[t * nb_c + blockIdx.x] = lh[t];
}

// multi-block exclusive scan (generic, over M ints)
__global__ __launch_bounds__(256) void scan_pass1(
    const int* __restrict__ deg, int* __restrict__ locals,
    int* __restrict__ bsum, int N)
{
    int t = threadIdx.x;
    int i = blockIdx.x * 256 + t;
    int v = (i < N) ? deg[i] : 0;
    int lane = t & 63, w = t >> 6;
    int s = v;
#pragma unroll
    for (int off = 1; off < 64; off <<= 1) {
        int u = __shfl_up(s, off);
        if (lane >= off) s += u;
    }
    __shared__ int wsum[4];
    if (lane == 63) wsum[w] = s;
    __syncthreads();
    int add = 0;
    for (int k = 0; k < w; k++) add += wsum[k];
    if (i < N) locals[i] = s + add - v;
    if (t == 255) bsum[blockIdx.x] = s + add;
}

__global__ __launch_bounds__(1024) void scan_pass2(
    const int* __restrict__ bsum, int* __restrict__ carry, int nb)
{
    __shared__ int sums[1024];
    int t = threadIdx.x;
    int chunk = (nb + 1023) >> 10;
    int beg = t * chunk;
    int end = beg + chunk; if (end > nb) end = nb;
    if (beg > nb) beg = nb;
    int s = 0;
    for (int i = beg; i < end; i++) s += bsum[i];
    sums[t] = s;
    __syncthreads();
    for (int off = 1; off < 1024; off <<= 1) {
        int v = (t >= off) ? sums[t - off] : 0;
        __syncthreads();
        sums[t] += v;
        __syncthreads();
    }
    int prefix = (t == 0) ? 0 : sums[t - 1];
    for (int i = beg; i < end; i++) { carry[i] = prefix; prefix += bsum[i]; }
}

__global__ __launch_bounds__(256) void scan_pass3b(
    const int* __restrict__ locals, const int* __restrict__ carry,
    int* __restrict__ S, int M, int E)
{
    int i = blockIdx.x * 256 + threadIdx.x;
    if (i < M) S[i] = locals[i] + carry[blockIdx.x];
    else if (i == M) S[M] = E;
}

// Pass C: ranked scatter into bucket-grouped packed array.
// Writes per (bucket,block) are contiguous -> line-coalesced runs.
__global__ __launch_bounds__(256) void bucket_scatter_kernel(
    const int* __restrict__ src, const int* __restrict__ dst,
    const int* __restrict__ S, unsigned* __restrict__ pk, int E, int nb_c)
{
    __shared__ int lbase[256];
    __shared__ int lrun[256];
    int t = threadIdx.x;
    lbase[t] = S[t * nb_c + blockIdx.x];
    lrun[t] = 0;
    __syncthreads();
    int base = blockIdx.x * (256 * ITEMS);
#pragma unroll
    for (int k = 0; k < ITEMS; k++) {
        int i = base + k * 256 + t;
        if (i < E) {
            int d = dst[i];
            int b = d >> 8;
            int r = atomicAdd(&lrun[b], 1);
            pk[lbase[b] + r] = ((unsigned)(d & 255) << 16) | (unsigned)src[i];
        }
    }
}

// Pass D: one block per bucket: per-dst counts -> offsets, then ranked
// placement of src (ushort) into the bucket's contiguous csr region.
__global__ __launch_bounds__(256) void bucket_finalize_kernel(
    const unsigned* __restrict__ pk, const int* __restrict__ S,
    int* __restrict__ offsets, unsigned short* __restrict__ csr16,
    int N, int E, int nb_c, int NB)
{
    __shared__ int lh[256];
    __shared__ int loff[256];
    __shared__ int lrun[256];
    int t = threadIdx.x;
    int b = blockIdx.x;
    int beg = S[b * nb_c];
    int endb = (b + 1 < NB) ? S[(b + 1) * nb_c] : E;
    lh[t] = 0; lrun[t] = 0;
    __syncthreads();
    for (int i = beg + t; i < endb; i += 256) atomicAdd(&lh[pk[i] >> 16], 1);
    __syncthreads();
    // inclusive scan of lh over 256 entries
    int v = lh[t];
    loff[t] = v;
    __syncthreads();
    for (int off = 1; off < 256; off <<= 1) {
        int u = (t >= off) ? loff[t - off] : 0;
        __syncthreads();
        loff[t] += u;
        __syncthreads();
    }
    int excl = loff[t] - v;
    int node = b * 256 + t;
    if (node < N) offsets[node] = beg + excl;
    if (b == NB - 1 && t == 0) offsets[N] = E;
    loff[t] = excl;   // own-index write only; no cross-reads until barrier
    __syncthreads();
    for (int i = beg + t; i < endb; i += 256) {
        unsigned w = pk[i];
        int d = (int)(w >> 16);
        int r = atomicAdd(&lrun[d], 1);
        csr16[beg + loff[d] + r] = (unsigned short)(w & 0xFFFFu);
    }
}

// ---------------------------------------------------------------------------
// Aggregate: h_new[v] = sum_{e: dst==v} sigmoid(a[src]+b[v]+be) * h[src]
// wave-per-node; 4x16 lane groups each read one full h-row (float4/lane).
__global__ __launch_bounds__(256) void aggregate_kernel(
    const float* __restrict__ h, const float* __restrict__ a_gate,
    const float* __restrict__ b_gate, const int* __restrict__ offsets,
    const unsigned short* __restrict__ csr16, const float* __restrict__ b_edge,
    unsigned short* __restrict__ hnew_bf, int N)
{
    int wid = threadIdx.x >> 6;
    int lane = threadIdx.x & 63;
    int sub = lane >> 4;     // edge slot 0..3
    int cg  = lane & 15;     // component group (4 floats)
    int v = blockIdx.x * 4 + wid;
    if (v >= N) return;

    int beg = offsets[v];
    int end = offsets[v + 1];
    float bv = b_gate[v] + b_edge[0];
    float4 acc = {0.f, 0.f, 0.f, 0.f};

    for (int cs = beg; cs < end; cs += 64) {
        int m = end - cs; if (m > 64) m = 64;
        int u = 0; float w = 0.f;
        if (lane < m) {
            u = (int)csr16[cs + lane];
            w = sigmoidf_(a_gate[u] + bv);
        }
        for (int j = 0; j < m; j += 4) {
            int e = j + sub;
            int uj = __shfl(u, e & 63);
            float wj = __shfl(w, e & 63);
            if (e >= m) wj = 0.f;
            float4 hv = *(const float4*)(h + (size_t)uj * H + cg * 4);
            acc.x += wj * hv.x; acc.y += wj * hv.y;
            acc.z += wj * hv.z; acc.w += wj * hv.w;
        }
    }
#pragma unroll
    for (int m = 16; m < 64; m <<= 1) {
        acc.x += __shfl_xor(acc.x, m);
        acc.y += __shfl_xor(acc.y, m);
        acc.z += __shfl_xor(acc.z, m);
        acc.w += __shfl_xor(acc.w, m);
    }
    if (sub == 0) {
        ushort4 o;
        o.x = f2bf(acc.x); o.y = f2bf(acc.y);
        o.z = f2bf(acc.z); o.w = f2bf(acc.w);
        *(ushort4*)(hnew_bf + (size_t)v * H + cg * 4) = o;
    }
}

// ---------------------------------------------------------------------------
// Fused GRU via MFMA bf16. Wave computes 16 nodes.
// C/D: col(j)=lane&15, row(node)=(lane>>4)*4+reg   [measured: m89]
__global__ __launch_bounds__(256) void gru_mfma_kernel(
    const unsigned short* __restrict__ x_bf,   // [N][64] bf16 (h_new)
    float* __restrict__ h,                     // [N][64] f32, in-place
    const unsigned short* __restrict__ wih_bf, // [192][64] bf16
    const unsigned short* __restrict__ whh_bf, // [192][64] bf16
    const float* __restrict__ bih, const float* __restrict__ bhh,
    const float* __restrict__ Wg,
    float* __restrict__ a_gate, float* __restrict__ b_gate, int N)
{
    int lane = threadIdx.x & 63;
    int wv = threadIdx.x >> 6;
    int c = lane & 15;      // j within tile / node-row for A
    int g = lane >> 4;      // k-group 0..3
    int nbase = blockIdx.x * 64 + wv * 16;
    if (nbase >= N) return;

    int nrow = nbase + c;
    int nclamp = nrow < N ? nrow : (N - 1);

    short8 ax[2], ah[2];
#pragma unroll
    for (int ch = 0; ch < 2; ch++) {
        ax[ch] = *(const short8*)(x_bf + (size_t)nclamp * H + ch * 32 + g * 8);
        const float4* ph = (const float4*)(h + (size_t)nclamp * H + ch * 32 + g * 8);
        float4 h0 = ph[0], h1 = ph[1];
        short8 t;
        t[0] = (short)f2bf(h0.x); t[1] = (short)f2bf(h0.y);
        t[2] = (short)f2bf(h0.z); t[3] = (short)f2bf(h0.w);
        t[4] = (short)f2bf(h1.x); t[5] = (short)f2bf(h1.y);
        t[6] = (short)f2bf(h1.z); t[7] = (short)f2bf(h1.w);
        ah[ch] = t;
    }

    f32x4 gi[12], gh[12];
#pragma unroll
    for (int jb = 0; jb < 12; jb++) {
        gi[jb] = (f32x4){0.f, 0.f, 0.f, 0.f};
        gh[jb] = (f32x4){0.f, 0.f, 0.f, 0.f};
    }

#pragma unroll
    for (int jb = 0; jb < 12; jb++) {
        const unsigned short* wi = wih_bf + (size_t)(jb * 16 + c) * H + g * 8;
        const unsigned short* wh = whh_bf + (size_t)(jb * 16 + c) * H + g * 8;
        short8 wi0 = *(const short8*)(wi);
        short8 wi1 = *(const short8*)(wi + 32);
        short8 wh0 = *(const short8*)(wh);
        short8 wh1 = *(const short8*)(wh + 32);
        gi[jb] = __builtin_amdgcn_mfma_f32_16x16x32_bf16(ax[0], wi0, gi[jb], 0, 0, 0);
        gi[jb] = __builtin_amdgcn_mfma_f32_16x16x32_bf16(ax[1], wi1, gi[jb], 0, 0, 0);
        gh[jb] = __builtin_amdgcn_mfma_f32_16x16x32_bf16(ah[0], wh0, gh[jb], 0, 0, 0);
        gh[jb] = __builtin_amdgcn_mfma_f32_16x16x32_bf16(ah[1], wh1, gh[jb], 0, 0, 0);
    }

    float pa[4] = {0.f, 0.f, 0.f, 0.f};
    float pb[4] = {0.f, 0.f, 0.f, 0.f};
#pragma unroll
    for (int jb = 0; jb < 4; jb++) {
        int j = jb * 16 + c;
        float br = bih[j] + bhh[j];
        float bz = bih[H + j] + bhh[H + j];
        float bin_ = bih[2 * H + j];
        float bhn_ = bhh[2 * H + j];
        float wga = Wg[j], wgb = Wg[H + j];
#pragma unroll
        for (int q = 0; q < 4; q++) {
            int node = nbase + g * 4 + q;
            float r = sigmoidf_(gi[jb][q] + gh[jb][q] + br);
            float z = sigmoidf_(gi[jb + 4][q] + gh[jb + 4][q] + bz);
            float nn = tanhf_(gi[jb + 8][q] + bin_ + r * (gh[jb + 8][q] + bhn_));
            size_t idx = (size_t)node * H + j;
            float hp = h[idx];
            float ho = (1.0f - z) * nn + z * hp;
            h[idx] = ho;
            pa[q] += ho * wga;
            pb[q] += ho * wgb;
        }
    }
#pragma unroll
    for (int m = 1; m < 16; m <<= 1) {
#pragma unroll
        for (int q = 0; q < 4; q++) {
            pa[q] += __shfl_xor(pa[q], m);
            pb[q] += __shfl_xor(pb[q], m);
        }
    }
    if (c == 0) {
#pragma unroll
        for (int q = 0; q < 4; q++) {
            int node = nbase + g * 4 + q;
            a_gate[node] = pa[q];
            b_gate[node] = pb[q];
        }
    }
}

// ---------------------------------------------------------------------------
// Final predictor: out[e] = pa[src] + pb[dst] + b_pred
__global__ __launch_bounds__(256) void predict_kernel(
    const int* __restrict__ src, const int* __restrict__ dst,
    const float* __restrict__ pa, const float* __restrict__ pb,
    const float* __restrict__ b_pred, float* __restrict__ out, int E)
{
    int e = blockIdx.x * 256 + threadIdx.x;
    if (e >= E) return;
    out[e] = pa[src[e]] + pb[dst[e]] + b_pred[0];
}

// ---------------------------------------------------------------------------
extern "C" void kernel_launch(void* const* d_in, const int* in_sizes, int n_in,
                              void* d_out, int out_size, void* d_ws, size_t ws_size,
                              hipStream_t stream) {
    const float* features = (const float*)d_in[0];
    const int*   src      = (const int*)d_in[1];
    const int*   dst      = (const int*)d_in[2];
    const float* W_in     = (const float*)d_in[3];
    const float* b_in     = (const float*)d_in[4];
    const float* W_edge   = (const float*)d_in[5];
    const float* b_edge   = (const float*)d_in[6];
    const float* Wih      = (const float*)d_in[7];
    const float* Whh      = (const float*)d_in[8];
    const float* bih      = (const float*)d_in[9];
    const float* bhh      = (const float*)d_in[10];
    const float* W_pred   = (const float*)d_in[11];
    const float* b_pred   = (const float*)d_in[12];
    float* out = (float*)d_out;

    int N = in_sizes[0] / 16;
    int E = in_sizes[1];
    int L = in_sizes[7] / (H3 * H);
    int per = L * H3 * H;

    int nb_nodes = (N + 255) / 256;
    int nb_edges = (E + 255) / 256;
    int nb_agg   = (N + 3) / 4;
    int nb_gru   = (N + 63) / 64;
    int nb_conv  = (2 * per + 255) / 256;

    int nb_c = (E + 256 * ITEMS - 1) / (256 * ITEMS);  // bucket hist/scatter blocks
    int NB   = (N + 255) / 256;                        // number of buckets
    int M    = 256 * nb_c;                             // flat bhist length
    int mb   = (M + 255) / 256;                        // scan blocks
    int nb_s3 = (M + 1 + 255) / 256;

    // workspace layout
    float* h = (float*)d_ws;                                         // N*64 f32
    unsigned short* hnew_bf = (unsigned short*)(h + (size_t)N * H);  // N*64 bf16
    unsigned short* w_bf = hnew_bf + (size_t)N * H;                  // 2*per bf16
    float* a_gate = (float*)(w_bf + 2 * per);                        // N
    float* b_gate = a_gate + N;                                      // N
    int* offsets  = (int*)(b_gate + N);                              // N+1
    unsigned* pk  = (unsigned*)(offsets + N + 1);                    // E
    unsigned short* csr16 = (unsigned short*)(pk + E);               // E (even)
    int* bhist = (int*)(csr16 + E);                                  // M
    int* bloc  = bhist + M;                                          // M
    int* sbh   = bloc + M;                                           // M+1
    int* bsum  = sbh + M + 1;                                        // mb
    int* carry = bsum + mb;                                          // mb

    input_gates_kernel<<<nb_nodes, 256, 0, stream>>>(
        features, W_in, b_in, W_edge, h, a_gate, b_gate, N);
    convert_w_kernel<<<nb_conv, 256, 0, stream>>>(Wih, Whh, w_bf, per);

    // CSR build (bucket sort)
    bucket_hist_kernel<<<nb_c, 256, 0, stream>>>(dst, bhist, E, nb_c);
    scan_pass1<<<mb, 256, 0, stream>>>(bhist, bloc, bsum, M);
    scan_pass2<<<1, 1024, 0, stream>>>(bsum, carry, mb);
    scan_pass3b<<<nb_s3, 256, 0, stream>>>(bloc, carry, sbh, M, E);
    bucket_scatter_kernel<<<nb_c, 256, 0, stream>>>(src, dst, sbh, pk, E, nb_c);
    bucket_finalize_kernel<<<NB, 256, 0, stream>>>(pk, sbh, offsets, csr16, N, E, nb_c, NB);

    for (int l = 0; l < L; l++) {
        aggregate_kernel<<<nb_agg, 256, 0, stream>>>(
            h, a_gate, b_gate, offsets, csr16, b_edge, hnew_bf, N);
        const float* Wg = (l < L - 1) ? W_edge : W_pred;
        gru_mfma_kernel<<<nb_gru, 256, 0, stream>>>(
            hnew_bf, h,
            w_bf + (size_t)l * H3 * H,
            w_bf + (size_t)per + (size_t)l * H3 * H,
            bih + (size_t)l * H3, bhh + (size_t)l * H3,
            Wg, a_gate, b_gate, N);
    }

    predict_kernel<<<nb_edges, 256, 0, stream>>>(src, dst, a_gate, b_gate, b_pred, out, E);
}

// Round 6
// 266.426 us; speedup vs baseline: 4.3276x; 1.0620x over previous
//
#include <hip/hip_runtime.h>
#include <hip/hip_bf16.h>

#define H 64
#define H3 192
#define ITEMS 16   // edges per thread in bucket hist/scatter (4096/block)

typedef __attribute__((ext_vector_type(8))) short short8;
typedef __attribute__((ext_vector_type(4))) float f32x4;

__device__ __forceinline__ float sigmoidf_(float x) {
    return 1.0f / (1.0f + __expf(-x));
}
__device__ __forceinline__ float tanhf_(float x) {
    float e = __expf(2.0f * x);
    return 1.0f - 2.0f / (e + 1.0f);
}
// f32 -> bf16 round-to-nearest-even (bit trick)
__device__ __forceinline__ unsigned short f2bf(float f) {
    unsigned u = __builtin_bit_cast(unsigned, f);
    u += 0x7FFFu + ((u >> 16) & 1u);
    return (unsigned short)(u >> 16);
}
__device__ __forceinline__ float bf2f(unsigned short s) {
    return __builtin_bit_cast(float, (unsigned)s << 16);
}

// ---------------------------------------------------------------------------
// K1: h = features @ W_in + b_in (f32 + bf16 copies); a/b gates for layer 0
__global__ __launch_bounds__(256) void input_gates_kernel(
    const float* __restrict__ feat, const float* __restrict__ Win,
    const float* __restrict__ bin, const float* __restrict__ Wg,
    float* __restrict__ h, unsigned short* __restrict__ h_bf,
    float* __restrict__ a_gate, float* __restrict__ b_gate,
    int N)
{
    __shared__ float sWin[16 * H];
    __shared__ float sbin[H];
    __shared__ float sWg[2 * H];
    int t = threadIdx.x;
    for (int i = t; i < 16 * H; i += 256) sWin[i] = Win[i];
    if (t < H) sbin[t] = bin[t];
    if (t < 2 * H) sWg[t] = Wg[t];
    __syncthreads();

    int n = blockIdx.x * 256 + t;
    if (n >= N) return;

    float f[16];
    const float4* fr = (const float4*)(feat + (size_t)n * 16);
#pragma unroll
    for (int i = 0; i < 4; i++) {
        float4 v = fr[i];
        f[4 * i + 0] = v.x; f[4 * i + 1] = v.y; f[4 * i + 2] = v.z; f[4 * i + 3] = v.w;
    }
    float a = 0.f, b = 0.f;
    float* hrow = h + (size_t)n * H;
    unsigned short* brow = h_bf + (size_t)n * H;
    for (int j = 0; j < H; j++) {
        float hj = sbin[j];
#pragma unroll
        for (int k = 0; k < 16; k++) hj += f[k] * sWin[k * H + j];
        hrow[j] = hj;
        brow[j] = f2bf(hj);
        a += hj * sWg[j];
        b += hj * sWg[H + j];
    }
    a_gate[n] = a;
    b_gate[n] = b;
}

// ---------------------------------------------------------------------------
// weights f32 -> bf16 (both Wih and Whh stacks)
__global__ __launch_bounds__(256) void convert_w_kernel(
    const float* __restrict__ Wih, const float* __restrict__ Whh,
    unsigned short* __restrict__ out, int per)
{
    int i = blockIdx.x * 256 + threadIdx.x;
    if (i < per) out[i] = f2bf(Wih[i]);
    else if (i < 2 * per) out[i] = f2bf(Whh[i - per]);
}

// ---------------------------------------------------------------------------
// CSR build via 2-level bucket sort. bucket = dst>>8.
__global__ __launch_bounds__(256) void bucket_hist_kernel(
    const int* __restrict__ dst, int* __restrict__ bhist, int E, int nb_c)
{
    __shared__ int lh[256];
    int t = threadIdx.x;
    lh[t] = 0;
    __syncthreads();
    int base = blockIdx.x * (256 * ITEMS);
#pragma unroll
    for (int k = 0; k < ITEMS; k++) {
        int i = base + k * 256 + t;
        if (i < E) atomicAdd(&lh[dst[i] >> 8], 1);
    }
    __syncthreads();
    bhist[t * nb_c + blockIdx.x] = lh[t];
}

// multi-block exclusive scan (generic, over M ints)
__global__ __launch_bounds__(256) void scan_pass1(
    const int* __restrict__ deg, int* __restrict__ locals,
    int* __restrict__ bsum, int N)
{
    int t = threadIdx.x;
    int i = blockIdx.x * 256 + t;
    int v = (i < N) ? deg[i] : 0;
    int lane = t & 63, w = t >> 6;
    int s = v;
#pragma unroll
    for (int off = 1; off < 64; off <<= 1) {
        int u = __shfl_up(s, off);
        if (lane >= off) s += u;
    }
    __shared__ int wsum[4];
    if (lane == 63) wsum[w] = s;
    __syncthreads();
    int add = 0;
    for (int k = 0; k < w; k++) add += wsum[k];
    if (i < N) locals[i] = s + add - v;
    if (t == 255) bsum[blockIdx.x] = s + add;
}

__global__ __launch_bounds__(1024) void scan_pass2(
    const int* __restrict__ bsum, int* __restrict__ carry, int nb)
{
    __shared__ int sums[1024];
    int t = threadIdx.x;
    int chunk = (nb + 1023) >> 10;
    int beg = t * chunk;
    int end = beg + chunk; if (end > nb) end = nb;
    if (beg > nb) beg = nb;
    int s = 0;
    for (int i = beg; i < end; i++) s += bsum[i];
    sums[t] = s;
    __syncthreads();
    for (int off = 1; off < 1024; off <<= 1) {
        int v = (t >= off) ? sums[t - off] : 0;
        __syncthreads();
        sums[t] += v;
        __syncthreads();
    }
    int prefix = (t == 0) ? 0 : sums[t - 1];
    for (int i = beg; i < end; i++) { carry[i] = prefix; prefix += bsum[i]; }
}

__global__ __launch_bounds__(256) void scan_pass3b(
    const int* __restrict__ locals, const int* __restrict__ carry,
    int* __restrict__ S, int M, int E)
{
    int i = blockIdx.x * 256 + threadIdx.x;
    if (i < M) S[i] = locals[i] + carry[blockIdx.x];
    else if (i == M) S[M] = E;
}

// Pass C: ranked scatter into bucket-grouped packed array.
__global__ __launch_bounds__(256) void bucket_scatter_kernel(
    const int* __restrict__ src, const int* __restrict__ dst,
    const int* __restrict__ S, unsigned* __restrict__ pk, int E, int nb_c)
{
    __shared__ int lbase[256];
    __shared__ int lrun[256];
    int t = threadIdx.x;
    lbase[t] = S[t * nb_c + blockIdx.x];
    lrun[t] = 0;
    __syncthreads();
    int base = blockIdx.x * (256 * ITEMS);
#pragma unroll
    for (int k = 0; k < ITEMS; k++) {
        int i = base + k * 256 + t;
        if (i < E) {
            int d = dst[i];
            int b = d >> 8;
            int r = atomicAdd(&lrun[b], 1);
            pk[lbase[b] + r] = ((unsigned)(d & 255) << 16) | (unsigned)src[i];
        }
    }
}

// Pass D: one block per bucket: per-dst counts -> offsets, ranked src (ushort)
__global__ __launch_bounds__(256) void bucket_finalize_kernel(
    const unsigned* __restrict__ pk, const int* __restrict__ S,
    int* __restrict__ offsets, unsigned short* __restrict__ csr16,
    int N, int E, int nb_c, int NB)
{
    __shared__ int lh[256];
    __shared__ int loff[256];
    __shared__ int lrun[256];
    int t = threadIdx.x;
    int b = blockIdx.x;
    int beg = S[b * nb_c];
    int endb = (b + 1 < NB) ? S[(b + 1) * nb_c] : E;
    lh[t] = 0; lrun[t] = 0;
    __syncthreads();
    for (int i = beg + t; i < endb; i += 256) atomicAdd(&lh[pk[i] >> 16], 1);
    __syncthreads();
    int v = lh[t];
    loff[t] = v;
    __syncthreads();
    for (int off = 1; off < 256; off <<= 1) {
        int u = (t >= off) ? loff[t - off] : 0;
        __syncthreads();
        loff[t] += u;
        __syncthreads();
    }
    int excl = loff[t] - v;
    int node = b * 256 + t;
    if (node < N) offsets[node] = beg + excl;
    if (b == NB - 1 && t == 0) offsets[N] = E;
    loff[t] = excl;
    __syncthreads();
    for (int i = beg + t; i < endb; i += 256) {
        unsigned w = pk[i];
        int d = (int)(w >> 16);
        int r = atomicAdd(&lrun[d], 1);
        csr16[beg + loff[d] + r] = (unsigned short)(w & 0xFFFFu);
    }
}

// ---------------------------------------------------------------------------
// Aggregate: h_new[v] = sum_{e: dst==v} sigmoid(a[src]+b[v]+be) * h[src]
// wave-per-node; 4x16 lane groups each read one full bf16 h-row (ushort4/lane)
__global__ __launch_bounds__(256) void aggregate_kernel(
    const unsigned short* __restrict__ h_bf, const float* __restrict__ a_gate,
    const float* __restrict__ b_gate, const int* __restrict__ offsets,
    const unsigned short* __restrict__ csr16, const float* __restrict__ b_edge,
    unsigned short* __restrict__ hnew_bf, int N)
{
    int wid = threadIdx.x >> 6;
    int lane = threadIdx.x & 63;
    int sub = lane >> 4;     // edge slot 0..3
    int cg  = lane & 15;     // component group (4 bf16)
    int v = blockIdx.x * 4 + wid;
    if (v >= N) return;

    int beg = offsets[v];
    int end = offsets[v + 1];
    float bv = b_gate[v] + b_edge[0];
    float4 acc = {0.f, 0.f, 0.f, 0.f};

    for (int cs = beg; cs < end; cs += 64) {
        int m = end - cs; if (m > 64) m = 64;
        int u = 0; float w = 0.f;
        if (lane < m) {
            u = (int)csr16[cs + lane];
            w = sigmoidf_(a_gate[u] + bv);
        }
        for (int j = 0; j < m; j += 4) {
            int e = j + sub;
            int uj = __shfl(u, e & 63);
            float wj = __shfl(w, e & 63);
            if (e >= m) wj = 0.f;
            ushort4 hv = *(const ushort4*)(h_bf + (size_t)uj * H + cg * 4);
            acc.x += wj * bf2f(hv.x); acc.y += wj * bf2f(hv.y);
            acc.z += wj * bf2f(hv.z); acc.w += wj * bf2f(hv.w);
        }
    }
#pragma unroll
    for (int m = 16; m < 64; m <<= 1) {
        acc.x += __shfl_xor(acc.x, m);
        acc.y += __shfl_xor(acc.y, m);
        acc.z += __shfl_xor(acc.z, m);
        acc.w += __shfl_xor(acc.w, m);
    }
    if (sub == 0) {
        ushort4 o;
        o.x = f2bf(acc.x); o.y = f2bf(acc.y);
        o.z = f2bf(acc.z); o.w = f2bf(acc.w);
        *(ushort4*)(hnew_bf + (size_t)v * H + cg * 4) = o;
    }
}

// ---------------------------------------------------------------------------
// Fused GRU via MFMA bf16. Wave computes 16 nodes.
// C/D: col(j)=lane&15, row(node)=(lane>>4)*4+reg   [measured: m89]
__global__ __launch_bounds__(256) void gru_mfma_kernel(
    const unsigned short* __restrict__ x_bf,   // [N][64] bf16 (h_new)
    float* __restrict__ h,                     // [N][64] f32, in-place
    unsigned short* __restrict__ h_bf,         // [N][64] bf16 shadow, in-place
    const unsigned short* __restrict__ wih_bf, // [192][64] bf16
    const unsigned short* __restrict__ whh_bf, // [192][64] bf16
    const float* __restrict__ bih, const float* __restrict__ bhh,
    const float* __restrict__ Wg,
    float* __restrict__ a_gate, float* __restrict__ b_gate, int N)
{
    int lane = threadIdx.x & 63;
    int wv = threadIdx.x >> 6;
    int c = lane & 15;      // j within tile / node-row for A
    int g = lane >> 4;      // k-group 0..3
    int nbase = blockIdx.x * 64 + wv * 16;
    if (nbase >= N) return;

    int nrow = nbase + c;
    int nclamp = nrow < N ? nrow : (N - 1);

    short8 ax[2], ah[2];
#pragma unroll
    for (int ch = 0; ch < 2; ch++) {
        ax[ch] = *(const short8*)(x_bf + (size_t)nclamp * H + ch * 32 + g * 8);
        ah[ch] = *(const short8*)(h_bf + (size_t)nclamp * H + ch * 32 + g * 8);
    }

    f32x4 gi[12], gh[12];
#pragma unroll
    for (int jb = 0; jb < 12; jb++) {
        gi[jb] = (f32x4){0.f, 0.f, 0.f, 0.f};
        gh[jb] = (f32x4){0.f, 0.f, 0.f, 0.f};
    }

#pragma unroll
    for (int jb = 0; jb < 12; jb++) {
        const unsigned short* wi = wih_bf + (size_t)(jb * 16 + c) * H + g * 8;
        const unsigned short* wh = whh_bf + (size_t)(jb * 16 + c) * H + g * 8;
        short8 wi0 = *(const short8*)(wi);
        short8 wi1 = *(const short8*)(wi + 32);
        short8 wh0 = *(const short8*)(wh);
        short8 wh1 = *(const short8*)(wh + 32);
        gi[jb] = __builtin_amdgcn_mfma_f32_16x16x32_bf16(ax[0], wi0, gi[jb], 0, 0, 0);
        gi[jb] = __builtin_amdgcn_mfma_f32_16x16x32_bf16(ax[1], wi1, gi[jb], 0, 0, 0);
        gh[jb] = __builtin_amdgcn_mfma_f32_16x16x32_bf16(ah[0], wh0, gh[jb], 0, 0, 0);
        gh[jb] = __builtin_amdgcn_mfma_f32_16x16x32_bf16(ah[1], wh1, gh[jb], 0, 0, 0);
    }

    float pa[4] = {0.f, 0.f, 0.f, 0.f};
    float pb[4] = {0.f, 0.f, 0.f, 0.f};
#pragma unroll
    for (int jb = 0; jb < 4; jb++) {
        int j = jb * 16 + c;
        float br = bih[j] + bhh[j];
        float bz = bih[H + j] + bhh[H + j];
        float bin_ = bih[2 * H + j];
        float bhn_ = bhh[2 * H + j];
        float wga = Wg[j], wgb = Wg[H + j];
#pragma unroll
        for (int q = 0; q < 4; q++) {
            int node = nbase + g * 4 + q;
            float r = sigmoidf_(gi[jb][q] + gh[jb][q] + br);
            float z = sigmoidf_(gi[jb + 4][q] + gh[jb + 4][q] + bz);
            float nn = tanhf_(gi[jb + 8][q] + bin_ + r * (gh[jb + 8][q] + bhn_));
            size_t idx = (size_t)node * H + j;
            float hp = h[idx];
            float ho = (1.0f - z) * nn + z * hp;
            h[idx] = ho;
            h_bf[idx] = f2bf(ho);
            pa[q] += ho * wga;
            pb[q] += ho * wgb;
        }
    }
#pragma unroll
    for (int m = 1; m < 16; m <<= 1) {
#pragma unroll
        for (int q = 0; q < 4; q++) {
            pa[q] += __shfl_xor(pa[q], m);
            pb[q] += __shfl_xor(pb[q], m);
        }
    }
    if (c == 0) {
#pragma unroll
        for (int q = 0; q < 4; q++) {
            int node = nbase + g * 4 + q;
            a_gate[node] = pa[q];
            b_gate[node] = pb[q];
        }
    }
}

// ---------------------------------------------------------------------------
// Final predictor: out[e] = pa[src] + pb[dst] + b_pred
__global__ __launch_bounds__(256) void predict_kernel(
    const int* __restrict__ src, const int* __restrict__ dst,
    const float* __restrict__ pa, const float* __restrict__ pb,
    const float* __restrict__ b_pred, float* __restrict__ out, int E)
{
    int e = blockIdx.x * 256 + threadIdx.x;
    if (e >= E) return;
    out[e] = pa[src[e]] + pb[dst[e]] + b_pred[0];
}

// ---------------------------------------------------------------------------
extern "C" void kernel_launch(void* const* d_in, const int* in_sizes, int n_in,
                              void* d_out, int out_size, void* d_ws, size_t ws_size,
                              hipStream_t stream) {
    const float* features = (const float*)d_in[0];
    const int*   src      = (const int*)d_in[1];
    const int*   dst      = (const int*)d_in[2];
    const float* W_in     = (const float*)d_in[3];
    const float* b_in     = (const float*)d_in[4];
    const float* W_edge   = (const float*)d_in[5];
    const float* b_edge   = (const float*)d_in[6];
    const float* Wih      = (const float*)d_in[7];
    const float* Whh      = (const float*)d_in[8];
    const float* bih      = (const float*)d_in[9];
    const float* bhh      = (const float*)d_in[10];
    const float* W_pred   = (const float*)d_in[11];
    const float* b_pred   = (const float*)d_in[12];
    float* out = (float*)d_out;

    int N = in_sizes[0] / 16;
    int E = in_sizes[1];
    int L = in_sizes[7] / (H3 * H);
    int per = L * H3 * H;

    int nb_nodes = (N + 255) / 256;
    int nb_edges = (E + 255) / 256;
    int nb_agg   = (N + 3) / 4;
    int nb_gru   = (N + 63) / 64;
    int nb_conv  = (2 * per + 255) / 256;

    int nb_c = (E + 256 * ITEMS - 1) / (256 * ITEMS);
    int NB   = (N + 255) / 256;
    int M    = 256 * nb_c;
    int mb   = (M + 255) / 256;
    int nb_s3 = (M + 1 + 255) / 256;

    // workspace layout
    float* h = (float*)d_ws;                                          // N*64 f32
    unsigned short* h_bf = (unsigned short*)(h + (size_t)N * H);      // N*64 bf16
    unsigned short* hnew_bf = h_bf + (size_t)N * H;                   // N*64 bf16
    unsigned short* w_bf = hnew_bf + (size_t)N * H;                   // 2*per bf16
    float* a_gate = (float*)(w_bf + 2 * per);                         // N
    float* b_gate = a_gate + N;                                       // N
    int* offsets  = (int*)(b_gate + N);                               // N+1
    unsigned* pk  = (unsigned*)(offsets + N + 1);                     // E
    unsigned short* csr16 = (unsigned short*)(pk + E);                // E (even)
    int* bhist = (int*)(csr16 + E);                                   // M
    int* bloc  = bhist + M;                                           // M
    int* sbh   = bloc + M;                                            // M+1
    int* bsum  = sbh + M + 1;                                         // mb
    int* carry = bsum + mb;                                           // mb

    input_gates_kernel<<<nb_nodes, 256, 0, stream>>>(
        features, W_in, b_in, W_edge, h, h_bf, a_gate, b_gate, N);
    convert_w_kernel<<<nb_conv, 256, 0, stream>>>(Wih, Whh, w_bf, per);

    // CSR build (bucket sort)
    bucket_hist_kernel<<<nb_c, 256, 0, stream>>>(dst, bhist, E, nb_c);
    scan_pass1<<<mb, 256, 0, stream>>>(bhist, bloc, bsum, M);
    scan_pass2<<<1, 1024, 0, stream>>>(bsum, carry, mb);
    scan_pass3b<<<nb_s3, 256, 0, stream>>>(bloc, carry, sbh, M, E);
    bucket_scatter_kernel<<<nb_c, 256, 0, stream>>>(src, dst, sbh, pk, E, nb_c);
    bucket_finalize_kernel<<<NB, 256, 0, stream>>>(pk, sbh, offsets, csr16, N, E, nb_c, NB);

    for (int l = 0; l < L; l++) {
        aggregate_kernel<<<nb_agg, 256, 0, stream>>>(
            h_bf, a_gate, b_gate, offsets, csr16, b_edge, hnew_bf, N);
        const float* Wg = (l < L - 1) ? W_edge : W_pred;
        gru_mfma_kernel<<<nb_gru, 256, 0, stream>>>(
            hnew_bf, h, h_bf,
            w_bf + (size_t)l * H3 * H,
            w_bf + (size_t)per + (size_t)l * H3 * H,
            bih + (size_t)l * H3, bhh + (size_t)l * H3,
            Wg, a_gate, b_gate, N);
    }

    predict_kernel<<<nb_edges, 256, 0, stream>>>(src, dst, a_gate, b_gate, b_pred, out, E);
}

// Round 7
// 260.338 us; speedup vs baseline: 4.4288x; 1.0234x over previous
//
#include <hip/hip_runtime.h>
#include <hip/hip_bf16.h>

#define H 64
#define H3 192
#define ITEMS 16   // edges per thread in bucket hist/scatter (4096/block)

typedef __attribute__((ext_vector_type(8))) short short8;
typedef __attribute__((ext_vector_type(4))) float f32x4;

__device__ __forceinline__ float sigmoidf_(float x) {
    return 1.0f / (1.0f + __expf(-x));
}
__device__ __forceinline__ float tanhf_(float x) {
    float e = __expf(2.0f * x);
    return 1.0f - 2.0f / (e + 1.0f);
}
// f32 -> bf16 round-to-nearest-even (bit trick)
__device__ __forceinline__ unsigned short f2bf(float f) {
    unsigned u = __builtin_bit_cast(unsigned, f);
    u += 0x7FFFu + ((u >> 16) & 1u);
    return (unsigned short)(u >> 16);
}
__device__ __forceinline__ float bf2f(unsigned short s) {
    return __builtin_bit_cast(float, (unsigned)s << 16);
}

// ---------------------------------------------------------------------------
// K1: h = features @ W_in + b_in (f32 + bf16 copies); a/b gates for layer 0
__global__ __launch_bounds__(256) void input_gates_kernel(
    const float* __restrict__ feat, const float* __restrict__ Win,
    const float* __restrict__ bin, const float* __restrict__ Wg,
    float* __restrict__ h, unsigned short* __restrict__ h_bf,
    float* __restrict__ a_gate, float* __restrict__ b_gate,
    int N)
{
    __shared__ float sWin[16 * H];
    __shared__ float sbin[H];
    __shared__ float sWg[2 * H];
    int t = threadIdx.x;
    for (int i = t; i < 16 * H; i += 256) sWin[i] = Win[i];
    if (t < H) sbin[t] = bin[t];
    if (t < 2 * H) sWg[t] = Wg[t];
    __syncthreads();

    int n = blockIdx.x * 256 + t;
    if (n >= N) return;

    float f[16];
    const float4* fr = (const float4*)(feat + (size_t)n * 16);
#pragma unroll
    for (int i = 0; i < 4; i++) {
        float4 v = fr[i];
        f[4 * i + 0] = v.x; f[4 * i + 1] = v.y; f[4 * i + 2] = v.z; f[4 * i + 3] = v.w;
    }
    float a = 0.f, b = 0.f;
    float* hrow = h + (size_t)n * H;
    unsigned short* brow = h_bf + (size_t)n * H;
    for (int j = 0; j < H; j++) {
        float hj = sbin[j];
#pragma unroll
        for (int k = 0; k < 16; k++) hj += f[k] * sWin[k * H + j];
        hrow[j] = hj;
        brow[j] = f2bf(hj);
        a += hj * sWg[j];
        b += hj * sWg[H + j];
    }
    a_gate[n] = a;
    b_gate[n] = b;
}

// ---------------------------------------------------------------------------
// weights f32 -> bf16 (both Wih and Whh stacks)
__global__ __launch_bounds__(256) void convert_w_kernel(
    const float* __restrict__ Wih, const float* __restrict__ Whh,
    unsigned short* __restrict__ out, int per)
{
    int i = blockIdx.x * 256 + threadIdx.x;
    if (i < per) out[i] = f2bf(Wih[i]);
    else if (i < 2 * per) out[i] = f2bf(Whh[i - per]);
}

// ---------------------------------------------------------------------------
// CSR build via 2-level bucket sort. bucket = dst>>8.
__global__ __launch_bounds__(256) void bucket_hist_kernel(
    const int* __restrict__ dst, int* __restrict__ bhist, int E, int nb_c)
{
    __shared__ int lh[256];
    int t = threadIdx.x;
    lh[t] = 0;
    __syncthreads();
    int base = blockIdx.x * (256 * ITEMS);
#pragma unroll
    for (int k = 0; k < ITEMS; k++) {
        int i = base + k * 256 + t;
        if (i < E) atomicAdd(&lh[dst[i] >> 8], 1);
    }
    __syncthreads();
    bhist[t * nb_c + blockIdx.x] = lh[t];
}

// multi-block exclusive scan (generic, over M ints)
__global__ __launch_bounds__(256) void scan_pass1(
    const int* __restrict__ deg, int* __restrict__ locals,
    int* __restrict__ bsum, int N)
{
    int t = threadIdx.x;
    int i = blockIdx.x * 256 + t;
    int v = (i < N) ? deg[i] : 0;
    int lane = t & 63, w = t >> 6;
    int s = v;
#pragma unroll
    for (int off = 1; off < 64; off <<= 1) {
        int u = __shfl_up(s, off);
        if (lane >= off) s += u;
    }
    __shared__ int wsum[4];
    if (lane == 63) wsum[w] = s;
    __syncthreads();
    int add = 0;
    for (int k = 0; k < w; k++) add += wsum[k];
    if (i < N) locals[i] = s + add - v;
    if (t == 255) bsum[blockIdx.x] = s + add;
}

__global__ __launch_bounds__(1024) void scan_pass2(
    const int* __restrict__ bsum, int* __restrict__ carry, int nb)
{
    __shared__ int sums[1024];
    int t = threadIdx.x;
    int chunk = (nb + 1023) >> 10;
    int beg = t * chunk;
    int end = beg + chunk; if (end > nb) end = nb;
    if (beg > nb) beg = nb;
    int s = 0;
    for (int i = beg; i < end; i++) s += bsum[i];
    sums[t] = s;
    __syncthreads();
    for (int off = 1; off < 1024; off <<= 1) {
        int v = (t >= off) ? sums[t - off] : 0;
        __syncthreads();
        sums[t] += v;
        __syncthreads();
    }
    int prefix = (t == 0) ? 0 : sums[t - 1];
    for (int i = beg; i < end; i++) { carry[i] = prefix; prefix += bsum[i]; }
}

__global__ __launch_bounds__(256) void scan_pass3b(
    const int* __restrict__ locals, const int* __restrict__ carry,
    int* __restrict__ S, int M, int E)
{
    int i = blockIdx.x * 256 + threadIdx.x;
    if (i < M) S[i] = locals[i] + carry[blockIdx.x];
    else if (i == M) S[M] = E;
}

// Pass C: ranked scatter into bucket-grouped packed array.
__global__ __launch_bounds__(256) void bucket_scatter_kernel(
    const int* __restrict__ src, const int* __restrict__ dst,
    const int* __restrict__ S, unsigned* __restrict__ pk, int E, int nb_c)
{
    __shared__ int lbase[256];
    __shared__ int lrun[256];
    int t = threadIdx.x;
    lbase[t] = S[t * nb_c + blockIdx.x];
    lrun[t] = 0;
    __syncthreads();
    int base = blockIdx.x * (256 * ITEMS);
#pragma unroll
    for (int k = 0; k < ITEMS; k++) {
        int i = base + k * 256 + t;
        if (i < E) {
            int d = dst[i];
            int b = d >> 8;
            int r = atomicAdd(&lrun[b], 1);
            pk[lbase[b] + r] = ((unsigned)(d & 255) << 16) | (unsigned)src[i];
        }
    }
}

// Pass D: one block per bucket: per-dst counts -> offsets, ranked src (ushort)
__global__ __launch_bounds__(256) void bucket_finalize_kernel(
    const unsigned* __restrict__ pk, const int* __restrict__ S,
    int* __restrict__ offsets, unsigned short* __restrict__ csr16,
    int N, int E, int nb_c, int NB)
{
    __shared__ int lh[256];
    __shared__ int loff[256];
    __shared__ int lrun[256];
    int t = threadIdx.x;
    int b = blockIdx.x;
    int beg = S[b * nb_c];
    int endb = (b + 1 < NB) ? S[(b + 1) * nb_c] : E;
    lh[t] = 0; lrun[t] = 0;
    __syncthreads();
    for (int i = beg + t; i < endb; i += 256) atomicAdd(&lh[pk[i] >> 16], 1);
    __syncthreads();
    int v = lh[t];
    loff[t] = v;
    __syncthreads();
    for (int off = 1; off < 256; off <<= 1) {
        int u = (t >= off) ? loff[t - off] : 0;
        __syncthreads();
        loff[t] += u;
        __syncthreads();
    }
    int excl = loff[t] - v;
    int node = b * 256 + t;
    if (node < N) offsets[node] = beg + excl;
    if (b == NB - 1 && t == 0) offsets[N] = E;
    loff[t] = excl;
    __syncthreads();
    for (int i = beg + t; i < endb; i += 256) {
        unsigned w = pk[i];
        int d = (int)(w >> 16);
        int r = atomicAdd(&lrun[d], 1);
        csr16[beg + loff[d] + r] = (unsigned short)(w & 0xFFFFu);
    }
}

// ---------------------------------------------------------------------------
// Aggregate: h_new[v] = sum_{e: dst==v} sigmoid(a[src]+b[v]+be) * h[src]
// wave-per-node; 8x8 lane groups each read one full bf16 h-row (short8/lane,
// 16B). 8 rows in flight per issue -> 2x the MLP of the ushort4 version.
__global__ __launch_bounds__(256) void aggregate_kernel(
    const unsigned short* __restrict__ h_bf, const float* __restrict__ a_gate,
    const float* __restrict__ b_gate, const int* __restrict__ offsets,
    const unsigned short* __restrict__ csr16, const float* __restrict__ b_edge,
    unsigned short* __restrict__ hnew_bf, int N)
{
    int wid = threadIdx.x >> 6;
    int lane = threadIdx.x & 63;
    int sub = lane >> 3;     // edge slot 0..7
    int cg  = lane & 7;      // component group (8 bf16 = 16B)
    int v = blockIdx.x * 4 + wid;
    if (v >= N) return;

    int beg = offsets[v];
    int end = offsets[v + 1];
    float bv = b_gate[v] + b_edge[0];
    float acc[8] = {0.f, 0.f, 0.f, 0.f, 0.f, 0.f, 0.f, 0.f};

    for (int cs = beg; cs < end; cs += 64) {
        int m = end - cs; if (m > 64) m = 64;
        int u = 0; float w = 0.f;
        if (lane < m) {
            u = (int)csr16[cs + lane];
            w = sigmoidf_(a_gate[u] + bv);
        }
        for (int j = 0; j < m; j += 8) {
            int e = j + sub;
            int uj = __shfl(u, e & 63);
            float wj = __shfl(w, e & 63);
            if (e >= m) wj = 0.f;
            short8 hv = *(const short8*)(h_bf + (size_t)uj * H + cg * 8);
#pragma unroll
            for (int k = 0; k < 8; k++)
                acc[k] += wj * bf2f((unsigned short)hv[k]);
        }
    }
    // reduce across the 8 sub-groups (lane bits 3,4,5)
#pragma unroll
    for (int mm = 8; mm < 64; mm <<= 1) {
#pragma unroll
        for (int k = 0; k < 8; k++)
            acc[k] += __shfl_xor(acc[k], mm);
    }
    if (sub == 0) {
        short8 o;
#pragma unroll
        for (int k = 0; k < 8; k++) o[k] = (short)f2bf(acc[k]);
        *(short8*)(hnew_bf + (size_t)v * H + cg * 8) = o;
    }
}

// ---------------------------------------------------------------------------
// Fused GRU via MFMA bf16. Wave computes 16 nodes.
// C/D: col(j)=lane&15, row(node)=(lane>>4)*4+reg   [measured: m89]
__global__ __launch_bounds__(256) void gru_mfma_kernel(
    const unsigned short* __restrict__ x_bf,   // [N][64] bf16 (h_new)
    float* __restrict__ h,                     // [N][64] f32, in-place
    unsigned short* __restrict__ h_bf,         // [N][64] bf16 shadow, in-place
    const unsigned short* __restrict__ wih_bf, // [192][64] bf16
    const unsigned short* __restrict__ whh_bf, // [192][64] bf16
    const float* __restrict__ bih, const float* __restrict__ bhh,
    const float* __restrict__ Wg,
    float* __restrict__ a_gate, float* __restrict__ b_gate, int N)
{
    int lane = threadIdx.x & 63;
    int wv = threadIdx.x >> 6;
    int c = lane & 15;      // j within tile / node-row for A
    int g = lane >> 4;      // k-group 0..3
    int nbase = blockIdx.x * 64 + wv * 16;
    if (nbase >= N) return;

    int nrow = nbase + c;
    int nclamp = nrow < N ? nrow : (N - 1);

    short8 ax[2], ah[2];
#pragma unroll
    for (int ch = 0; ch < 2; ch++) {
        ax[ch] = *(const short8*)(x_bf + (size_t)nclamp * H + ch * 32 + g * 8);
        ah[ch] = *(const short8*)(h_bf + (size_t)nclamp * H + ch * 32 + g * 8);
    }

    f32x4 gi[12], gh[12];
#pragma unroll
    for (int jb = 0; jb < 12; jb++) {
        gi[jb] = (f32x4){0.f, 0.f, 0.f, 0.f};
        gh[jb] = (f32x4){0.f, 0.f, 0.f, 0.f};
    }

#pragma unroll
    for (int jb = 0; jb < 12; jb++) {
        const unsigned short* wi = wih_bf + (size_t)(jb * 16 + c) * H + g * 8;
        const unsigned short* wh = whh_bf + (size_t)(jb * 16 + c) * H + g * 8;
        short8 wi0 = *(const short8*)(wi);
        short8 wi1 = *(const short8*)(wi + 32);
        short8 wh0 = *(const short8*)(wh);
        short8 wh1 = *(const short8*)(wh + 32);
        gi[jb] = __builtin_amdgcn_mfma_f32_16x16x32_bf16(ax[0], wi0, gi[jb], 0, 0, 0);
        gi[jb] = __builtin_amdgcn_mfma_f32_16x16x32_bf16(ax[1], wi1, gi[jb], 0, 0, 0);
        gh[jb] = __builtin_amdgcn_mfma_f32_16x16x32_bf16(ah[0], wh0, gh[jb], 0, 0, 0);
        gh[jb] = __builtin_amdgcn_mfma_f32_16x16x32_bf16(ah[1], wh1, gh[jb], 0, 0, 0);
    }

    float pa[4] = {0.f, 0.f, 0.f, 0.f};
    float pb[4] = {0.f, 0.f, 0.f, 0.f};
#pragma unroll
    for (int jb = 0; jb < 4; jb++) {
        int j = jb * 16 + c;
        float br = bih[j] + bhh[j];
        float bz = bih[H + j] + bhh[H + j];
        float bin_ = bih[2 * H + j];
        float bhn_ = bhh[2 * H + j];
        float wga = Wg[j], wgb = Wg[H + j];
#pragma unroll
        for (int q = 0; q < 4; q++) {
            int node = nbase + g * 4 + q;
            float r = sigmoidf_(gi[jb][q] + gh[jb][q] + br);
            float z = sigmoidf_(gi[jb + 4][q] + gh[jb + 4][q] + bz);
            float nn = tanhf_(gi[jb + 8][q] + bin_ + r * (gh[jb + 8][q] + bhn_));
            size_t idx = (size_t)node * H + j;
            float hp = h[idx];
            float ho = (1.0f - z) * nn + z * hp;
            h[idx] = ho;
            h_bf[idx] = f2bf(ho);
            pa[q] += ho * wga;
            pb[q] += ho * wgb;
        }
    }
#pragma unroll
    for (int m = 1; m < 16; m <<= 1) {
#pragma unroll
        for (int q = 0; q < 4; q++) {
            pa[q] += __shfl_xor(pa[q], m);
            pb[q] += __shfl_xor(pb[q], m);
        }
    }
    if (c == 0) {
#pragma unroll
        for (int q = 0; q < 4; q++) {
            int node = nbase + g * 4 + q;
            a_gate[node] = pa[q];
            b_gate[node] = pb[q];
        }
    }
}

// ---------------------------------------------------------------------------
// Final predictor: out[e] = pa[src] + pb[dst] + b_pred  (4 edges/thread)
__global__ __launch_bounds__(256) void predict_kernel(
    const int* __restrict__ src, const int* __restrict__ dst,
    const float* __restrict__ pa, const float* __restrict__ pb,
    const float* __restrict__ b_pred, float* __restrict__ out, int E)
{
    int e4 = (blockIdx.x * 256 + threadIdx.x) * 4;
    float bp = b_pred[0];
    if (e4 + 3 < E) {
        int4 s = *(const int4*)(src + e4);
        int4 d = *(const int4*)(dst + e4);
        float4 o;
        o.x = pa[s.x] + pb[d.x] + bp;
        o.y = pa[s.y] + pb[d.y] + bp;
        o.z = pa[s.z] + pb[d.z] + bp;
        o.w = pa[s.w] + pb[d.w] + bp;
        *(float4*)(out + e4) = o;
    } else {
        for (int e = e4; e < E; e++)
            out[e] = pa[src[e]] + pb[dst[e]] + bp;
    }
}

// ---------------------------------------------------------------------------
extern "C" void kernel_launch(void* const* d_in, const int* in_sizes, int n_in,
                              void* d_out, int out_size, void* d_ws, size_t ws_size,
                              hipStream_t stream) {
    const float* features = (const float*)d_in[0];
    const int*   src      = (const int*)d_in[1];
    const int*   dst      = (const int*)d_in[2];
    const float* W_in     = (const float*)d_in[3];
    const float* b_in     = (const float*)d_in[4];
    const float* W_edge   = (const float*)d_in[5];
    const float* b_edge   = (const float*)d_in[6];
    const float* Wih      = (const float*)d_in[7];
    const float* Whh      = (const float*)d_in[8];
    const float* bih      = (const float*)d_in[9];
    const float* bhh      = (const float*)d_in[10];
    const float* W_pred   = (const float*)d_in[11];
    const float* b_pred   = (const float*)d_in[12];
    float* out = (float*)d_out;

    int N = in_sizes[0] / 16;
    int E = in_sizes[1];
    int L = in_sizes[7] / (H3 * H);
    int per = L * H3 * H;

    int nb_nodes = (N + 255) / 256;
    int nb_agg   = (N + 3) / 4;
    int nb_gru   = (N + 63) / 64;
    int nb_conv  = (2 * per + 255) / 256;
    int nb_pred  = (E + 1023) / 1024;

    int nb_c = (E + 256 * ITEMS - 1) / (256 * ITEMS);
    int NB   = (N + 255) / 256;
    int M    = 256 * nb_c;
    int mb   = (M + 255) / 256;
    int nb_s3 = (M + 1 + 255) / 256;

    // workspace layout
    float* h = (float*)d_ws;                                          // N*64 f32
    unsigned short* h_bf = (unsigned short*)(h + (size_t)N * H);      // N*64 bf16
    unsigned short* hnew_bf = h_bf + (size_t)N * H;                   // N*64 bf16
    unsigned short* w_bf = hnew_bf + (size_t)N * H;                   // 2*per bf16
    float* a_gate = (float*)(w_bf + 2 * per);                         // N
    float* b_gate = a_gate + N;                                       // N
    int* offsets  = (int*)(b_gate + N);                               // N+1
    unsigned* pk  = (unsigned*)(offsets + N + 1);                     // E
    unsigned short* csr16 = (unsigned short*)(pk + E);                // E (even)
    int* bhist = (int*)(csr16 + E);                                   // M
    int* bloc  = bhist + M;                                           // M
    int* sbh   = bloc + M;                                            // M+1
    int* bsum  = sbh + M + 1;                                         // mb
    int* carry = bsum + mb;                                           // mb

    input_gates_kernel<<<nb_nodes, 256, 0, stream>>>(
        features, W_in, b_in, W_edge, h, h_bf, a_gate, b_gate, N);
    convert_w_kernel<<<nb_conv, 256, 0, stream>>>(Wih, Whh, w_bf, per);

    // CSR build (bucket sort)
    bucket_hist_kernel<<<nb_c, 256, 0, stream>>>(dst, bhist, E, nb_c);
    scan_pass1<<<mb, 256, 0, stream>>>(bhist, bloc, bsum, M);
    scan_pass2<<<1, 1024, 0, stream>>>(bsum, carry, mb);
    scan_pass3b<<<nb_s3, 256, 0, stream>>>(bloc, carry, sbh, M, E);
    bucket_scatter_kernel<<<nb_c, 256, 0, stream>>>(src, dst, sbh, pk, E, nb_c);
    bucket_finalize_kernel<<<NB, 256, 0, stream>>>(pk, sbh, offsets, csr16, N, E, nb_c, NB);

    for (int l = 0; l < L; l++) {
        aggregate_kernel<<<nb_agg, 256, 0, stream>>>(
            h_bf, a_gate, b_gate, offsets, csr16, b_edge, hnew_bf, N);
        const float* Wg = (l < L - 1) ? W_edge : W_pred;
        gru_mfma_kernel<<<nb_gru, 256, 0, stream>>>(
            hnew_bf, h, h_bf,
            w_bf + (size_t)l * H3 * H,
            w_bf + (size_t)per + (size_t)l * H3 * H,
            bih + (size_t)l * H3, bhh + (size_t)l * H3,
            Wg, a_gate, b_gate, N);
    }

    predict_kernel<<<nb_pred, 256, 0, stream>>>(src, dst, a_gate, b_gate, b_pred, out, E);
}

// Round 8
// 247.134 us; speedup vs baseline: 4.6654x; 1.0534x over previous
//
#include <hip/hip_runtime.h>
#include <hip/hip_bf16.h>

#define H 64
#define H3 192
#define ITEMS 16   // edges per thread in bucket hist/scatter (4096/block)

typedef __attribute__((ext_vector_type(8))) short short8;
typedef __attribute__((ext_vector_type(4))) float f32x4;

__device__ __forceinline__ float sigmoidf_(float x) {
    return 1.0f / (1.0f + __expf(-x));
}
__device__ __forceinline__ float tanhf_(float x) {
    float e = __expf(2.0f * x);
    return 1.0f - 2.0f / (e + 1.0f);
}
// f32 -> bf16 round-to-nearest-even (bit trick)
__device__ __forceinline__ unsigned short f2bf(float f) {
    unsigned u = __builtin_bit_cast(unsigned, f);
    u += 0x7FFFu + ((u >> 16) & 1u);
    return (unsigned short)(u >> 16);
}
__device__ __forceinline__ float bf2f(unsigned short s) {
    return __builtin_bit_cast(float, (unsigned)s << 16);
}

// ---------------------------------------------------------------------------
// Fused setup: [0, nbA): input linear + gates; [nbA, nbA+nbB): weight convert;
// [nbA+nbB, ...): bucket histogram. All three are independent.
__global__ __launch_bounds__(256) void setup_kernel(
    const float* __restrict__ feat, const float* __restrict__ Win,
    const float* __restrict__ bin, const float* __restrict__ Wg,
    float* __restrict__ h, unsigned short* __restrict__ h_bf,
    float* __restrict__ a_gate, float* __restrict__ b_gate,
    const float* __restrict__ Wih, const float* __restrict__ Whh,
    unsigned short* __restrict__ w_bf,
    const int* __restrict__ dst, int* __restrict__ bhist,
    int N, int E, int per, int nbA, int nbB, int nb_c)
{
    int bid = blockIdx.x;
    int t = threadIdx.x;
    if (bid < nbA) {
        // ---- input linear + layer-0 gates ----
        __shared__ float sWin[16 * H];
        __shared__ float sbin[H];
        __shared__ float sWg[2 * H];
        for (int i = t; i < 16 * H; i += 256) sWin[i] = Win[i];
        if (t < H) sbin[t] = bin[t];
        if (t < 2 * H) sWg[t] = Wg[t];
        __syncthreads();

        int n = bid * 256 + t;
        if (n >= N) return;

        float f[16];
        const float4* fr = (const float4*)(feat + (size_t)n * 16);
#pragma unroll
        for (int i = 0; i < 4; i++) {
            float4 v = fr[i];
            f[4 * i + 0] = v.x; f[4 * i + 1] = v.y;
            f[4 * i + 2] = v.z; f[4 * i + 3] = v.w;
        }
        float a = 0.f, b = 0.f;
        float* hrow = h + (size_t)n * H;
        unsigned short* brow = h_bf + (size_t)n * H;
        for (int j = 0; j < H; j++) {
            float hj = sbin[j];
#pragma unroll
            for (int k = 0; k < 16; k++) hj += f[k] * sWin[k * H + j];
            hrow[j] = hj;
            brow[j] = f2bf(hj);
            a += hj * sWg[j];
            b += hj * sWg[H + j];
        }
        a_gate[n] = a;
        b_gate[n] = b;
    } else if (bid < nbA + nbB) {
        // ---- weights f32 -> bf16 ----
        int i = (bid - nbA) * 256 + t;
        if (i < per) w_bf[i] = f2bf(Wih[i]);
        else if (i < 2 * per) w_bf[i] = f2bf(Whh[i - per]);
    } else {
        // ---- bucket histogram (bucket = dst>>8) ----
        __shared__ int lh[256];
        lh[t] = 0;
        __syncthreads();
        int base = (bid - nbA - nbB) * (256 * ITEMS);
#pragma unroll
        for (int k = 0; k < ITEMS; k++) {
            int i = base + k * 256 + t;
            if (i < E) atomicAdd(&lh[dst[i] >> 8], 1);
        }
        __syncthreads();
        bhist[t * nb_c + (bid - nbA - nbB)] = lh[t];
    }
}

// ---------------------------------------------------------------------------
// multi-block exclusive scan pass 1 (block-local prefix + block totals)
__global__ __launch_bounds__(256) void scan_pass1(
    const int* __restrict__ deg, int* __restrict__ locals,
    int* __restrict__ bsum, int N)
{
    int t = threadIdx.x;
    int i = blockIdx.x * 256 + t;
    int v = (i < N) ? deg[i] : 0;
    int lane = t & 63, w = t >> 6;
    int s = v;
#pragma unroll
    for (int off = 1; off < 64; off <<= 1) {
        int u = __shfl_up(s, off);
        if (lane >= off) s += u;
    }
    __shared__ int wsum[4];
    if (lane == 63) wsum[w] = s;
    __syncthreads();
    int add = 0;
    for (int k = 0; k < w; k++) add += wsum[k];
    if (i < N) locals[i] = s + add - v;
    if (t == 255) bsum[blockIdx.x] = s + add;
}

// pass 3 with per-block carry recompute (folds away the middle scan kernel):
// carry(b) = sum of bsum[0..b), computed by a block-wide reduction.
__global__ __launch_bounds__(256) void scan_pass3c(
    const int* __restrict__ locals, const int* __restrict__ bsum,
    int* __restrict__ S, int M, int E, int mb)
{
    int t = threadIdx.x;
    int b = blockIdx.x;
    int v = 0;
    for (int k = t; k < b && k < mb; k += 256) v += bsum[k];
#pragma unroll
    for (int off = 32; off >= 1; off >>= 1) v += __shfl_xor(v, off);
    __shared__ int ws[4];
    if ((t & 63) == 0) ws[t >> 6] = v;
    __syncthreads();
    int carry = ws[0] + ws[1] + ws[2] + ws[3];

    int i = b * 256 + t;
    if (i < M) S[i] = locals[i] + carry;
    else if (i == M) S[M] = E;
}

// Pass C: ranked scatter into bucket-grouped packed array.
__global__ __launch_bounds__(256) void bucket_scatter_kernel(
    const int* __restrict__ src, const int* __restrict__ dst,
    const int* __restrict__ S, unsigned* __restrict__ pk, int E, int nb_c)
{
    __shared__ int lbase[256];
    __shared__ int lrun[256];
    int t = threadIdx.x;
    lbase[t] = S[t * nb_c + blockIdx.x];
    lrun[t] = 0;
    __syncthreads();
    int base = blockIdx.x * (256 * ITEMS);
#pragma unroll
    for (int k = 0; k < ITEMS; k++) {
        int i = base + k * 256 + t;
        if (i < E) {
            int d = dst[i];
            int b = d >> 8;
            int r = atomicAdd(&lrun[b], 1);
            pk[lbase[b] + r] = ((unsigned)(d & 255) << 16) | (unsigned)src[i];
        }
    }
}

// Pass D: one block per bucket: per-dst counts -> offsets, ranked src (ushort)
__global__ __launch_bounds__(256) void bucket_finalize_kernel(
    const unsigned* __restrict__ pk, const int* __restrict__ S,
    int* __restrict__ offsets, unsigned short* __restrict__ csr16,
    int N, int E, int nb_c, int NB)
{
    __shared__ int lh[256];
    __shared__ int loff[256];
    __shared__ int lrun[256];
    int t = threadIdx.x;
    int b = blockIdx.x;
    int beg = S[b * nb_c];
    int endb = (b + 1 < NB) ? S[(b + 1) * nb_c] : E;
    lh[t] = 0; lrun[t] = 0;
    __syncthreads();
    for (int i = beg + t; i < endb; i += 256) atomicAdd(&lh[pk[i] >> 16], 1);
    __syncthreads();
    int v = lh[t];
    loff[t] = v;
    __syncthreads();
    for (int off = 1; off < 256; off <<= 1) {
        int u = (t >= off) ? loff[t - off] : 0;
        __syncthreads();
        loff[t] += u;
        __syncthreads();
    }
    int excl = loff[t] - v;
    int node = b * 256 + t;
    if (node < N) offsets[node] = beg + excl;
    if (b == NB - 1 && t == 0) offsets[N] = E;
    loff[t] = excl;
    __syncthreads();
    for (int i = beg + t; i < endb; i += 256) {
        unsigned w = pk[i];
        int d = (int)(w >> 16);
        int r = atomicAdd(&lrun[d], 1);
        csr16[beg + loff[d] + r] = (unsigned short)(w & 0xFFFFu);
    }
}

// ---------------------------------------------------------------------------
// Aggregate: h_new[v] = sum_{e: dst==v} sigmoid(a[src]+b[v]+be) * h[src]
// wave-per-node; 8x8 lane groups, 2x unrolled -> 16 rows in flight per iter.
__global__ __launch_bounds__(256) void aggregate_kernel(
    const unsigned short* __restrict__ h_bf, const float* __restrict__ a_gate,
    const float* __restrict__ b_gate, const int* __restrict__ offsets,
    const unsigned short* __restrict__ csr16, const float* __restrict__ b_edge,
    unsigned short* __restrict__ hnew_bf, int N)
{
    int wid = threadIdx.x >> 6;
    int lane = threadIdx.x & 63;
    int sub = lane >> 3;     // edge slot 0..7
    int cg  = lane & 7;      // component group (8 bf16 = 16B)
    int v = blockIdx.x * 4 + wid;
    if (v >= N) return;

    int beg = offsets[v];
    int end = offsets[v + 1];
    float bv = b_gate[v] + b_edge[0];
    float acc0[8] = {0.f, 0.f, 0.f, 0.f, 0.f, 0.f, 0.f, 0.f};
    float acc1[8] = {0.f, 0.f, 0.f, 0.f, 0.f, 0.f, 0.f, 0.f};

    for (int cs = beg; cs < end; cs += 64) {
        int m = end - cs; if (m > 64) m = 64;
        int u = 0; float w = 0.f;
        if (lane < m) {
            u = (int)csr16[cs + lane];
            w = sigmoidf_(a_gate[u] + bv);
        }
        for (int j = 0; j < m; j += 16) {
            int e0 = j + sub, e1 = j + 8 + sub;
            int u0 = __shfl(u, e0 & 63);
            float w0 = __shfl(w, e0 & 63);
            int u1 = __shfl(u, e1 & 63);
            float w1 = __shfl(w, e1 & 63);
            if (e0 >= m) w0 = 0.f;
            if (e1 >= m) w1 = 0.f;
            short8 hv0 = *(const short8*)(h_bf + (size_t)u0 * H + cg * 8);
            short8 hv1 = *(const short8*)(h_bf + (size_t)u1 * H + cg * 8);
#pragma unroll
            for (int k = 0; k < 8; k++)
                acc0[k] += w0 * bf2f((unsigned short)hv0[k]);
#pragma unroll
            for (int k = 0; k < 8; k++)
                acc1[k] += w1 * bf2f((unsigned short)hv1[k]);
        }
    }
#pragma unroll
    for (int k = 0; k < 8; k++) acc0[k] += acc1[k];
    // reduce across the 8 sub-groups (lane bits 3,4,5)
#pragma unroll
    for (int mm = 8; mm < 64; mm <<= 1) {
#pragma unroll
        for (int k = 0; k < 8; k++)
            acc0[k] += __shfl_xor(acc0[k], mm);
    }
    if (sub == 0) {
        short8 o;
#pragma unroll
        for (int k = 0; k < 8; k++) o[k] = (short)f2bf(acc0[k]);
        *(short8*)(hnew_bf + (size_t)v * H + cg * 8) = o;
    }
}

// ---------------------------------------------------------------------------
// Fused GRU via MFMA bf16. Wave computes 16 nodes.
// C/D: col(j)=lane&15, row(node)=(lane>>4)*4+reg   [measured: m89]
__global__ __launch_bounds__(256) void gru_mfma_kernel(
    const unsigned short* __restrict__ x_bf,   // [N][64] bf16 (h_new)
    float* __restrict__ h,                     // [N][64] f32, in-place
    unsigned short* __restrict__ h_bf,         // [N][64] bf16 shadow, in-place
    const unsigned short* __restrict__ wih_bf, // [192][64] bf16
    const unsigned short* __restrict__ whh_bf, // [192][64] bf16
    const float* __restrict__ bih, const float* __restrict__ bhh,
    const float* __restrict__ Wg,
    float* __restrict__ a_gate, float* __restrict__ b_gate, int N)
{
    int lane = threadIdx.x & 63;
    int wv = threadIdx.x >> 6;
    int c = lane & 15;      // j within tile / node-row for A
    int g = lane >> 4;      // k-group 0..3
    int nbase = blockIdx.x * 64 + wv * 16;
    if (nbase >= N) return;

    int nrow = nbase + c;
    int nclamp = nrow < N ? nrow : (N - 1);

    short8 ax[2], ah[2];
#pragma unroll
    for (int ch = 0; ch < 2; ch++) {
        ax[ch] = *(const short8*)(x_bf + (size_t)nclamp * H + ch * 32 + g * 8);
        ah[ch] = *(const short8*)(h_bf + (size_t)nclamp * H + ch * 32 + g * 8);
    }

    f32x4 gi[12], gh[12];
#pragma unroll
    for (int jb = 0; jb < 12; jb++) {
        gi[jb] = (f32x4){0.f, 0.f, 0.f, 0.f};
        gh[jb] = (f32x4){0.f, 0.f, 0.f, 0.f};
    }

#pragma unroll
    for (int jb = 0; jb < 12; jb++) {
        const unsigned short* wi = wih_bf + (size_t)(jb * 16 + c) * H + g * 8;
        const unsigned short* wh = whh_bf + (size_t)(jb * 16 + c) * H + g * 8;
        short8 wi0 = *(const short8*)(wi);
        short8 wi1 = *(const short8*)(wi + 32);
        short8 wh0 = *(const short8*)(wh);
        short8 wh1 = *(const short8*)(wh + 32);
        gi[jb] = __builtin_amdgcn_mfma_f32_16x16x32_bf16(ax[0], wi0, gi[jb], 0, 0, 0);
        gi[jb] = __builtin_amdgcn_mfma_f32_16x16x32_bf16(ax[1], wi1, gi[jb], 0, 0, 0);
        gh[jb] = __builtin_amdgcn_mfma_f32_16x16x32_bf16(ah[0], wh0, gh[jb], 0, 0, 0);
        gh[jb] = __builtin_amdgcn_mfma_f32_16x16x32_bf16(ah[1], wh1, gh[jb], 0, 0, 0);
    }

    float pa[4] = {0.f, 0.f, 0.f, 0.f};
    float pb[4] = {0.f, 0.f, 0.f, 0.f};
#pragma unroll
    for (int jb = 0; jb < 4; jb++) {
        int j = jb * 16 + c;
        float br = bih[j] + bhh[j];
        float bz = bih[H + j] + bhh[H + j];
        float bin_ = bih[2 * H + j];
        float bhn_ = bhh[2 * H + j];
        float wga = Wg[j], wgb = Wg[H + j];
#pragma unroll
        for (int q = 0; q < 4; q++) {
            int node = nbase + g * 4 + q;
            float r = sigmoidf_(gi[jb][q] + gh[jb][q] + br);
            float z = sigmoidf_(gi[jb + 4][q] + gh[jb + 4][q] + bz);
            float nn = tanhf_(gi[jb + 8][q] + bin_ + r * (gh[jb + 8][q] + bhn_));
            size_t idx = (size_t)node * H + j;
            float hp = h[idx];
            float ho = (1.0f - z) * nn + z * hp;
            h[idx] = ho;
            h_bf[idx] = f2bf(ho);
            pa[q] += ho * wga;
            pb[q] += ho * wgb;
        }
    }
#pragma unroll
    for (int m = 1; m < 16; m <<= 1) {
#pragma unroll
        for (int q = 0; q < 4; q++) {
            pa[q] += __shfl_xor(pa[q], m);
            pb[q] += __shfl_xor(pb[q], m);
        }
    }
    if (c == 0) {
#pragma unroll
        for (int q = 0; q < 4; q++) {
            int node = nbase + g * 4 + q;
            a_gate[node] = pa[q];
            b_gate[node] = pb[q];
        }
    }
}

// ---------------------------------------------------------------------------
// Final predictor: out[e] = pa[src] + pb[dst] + b_pred  (4 edges/thread)
__global__ __launch_bounds__(256) void predict_kernel(
    const int* __restrict__ src, const int* __restrict__ dst,
    const float* __restrict__ pa, const float* __restrict__ pb,
    const float* __restrict__ b_pred, float* __restrict__ out, int E)
{
    int e4 = (blockIdx.x * 256 + threadIdx.x) * 4;
    float bp = b_pred[0];
    if (e4 + 3 < E) {
        int4 s = *(const int4*)(src + e4);
        int4 d = *(const int4*)(dst + e4);
        float4 o;
        o.x = pa[s.x] + pb[d.x] + bp;
        o.y = pa[s.y] + pb[d.y] + bp;
        o.z = pa[s.z] + pb[d.z] + bp;
        o.w = pa[s.w] + pb[d.w] + bp;
        *(float4*)(out + e4) = o;
    } else {
        for (int e = e4; e < E; e++)
            out[e] = pa[src[e]] + pb[dst[e]] + bp;
    }
}

// ---------------------------------------------------------------------------
extern "C" void kernel_launch(void* const* d_in, const int* in_sizes, int n_in,
                              void* d_out, int out_size, void* d_ws, size_t ws_size,
                              hipStream_t stream) {
    const float* features = (const float*)d_in[0];
    const int*   src      = (const int*)d_in[1];
    const int*   dst      = (const int*)d_in[2];
    const float* W_in     = (const float*)d_in[3];
    const float* b_in     = (const float*)d_in[4];
    const float* W_edge   = (const float*)d_in[5];
    const float* b_edge   = (const float*)d_in[6];
    const float* Wih      = (const float*)d_in[7];
    const float* Whh      = (const float*)d_in[8];
    const float* bih      = (const float*)d_in[9];
    const float* bhh      = (const float*)d_in[10];
    const float* W_pred   = (const float*)d_in[11];
    const float* b_pred   = (const float*)d_in[12];
    float* out = (float*)d_out;

    int N = in_sizes[0] / 16;
    int E = in_sizes[1];
    int L = in_sizes[7] / (H3 * H);
    int per = L * H3 * H;

    int nb_nodes = (N + 255) / 256;
    int nb_agg   = (N + 3) / 4;
    int nb_gru   = (N + 63) / 64;
    int nb_conv  = (2 * per + 255) / 256;
    int nb_pred  = (E + 1023) / 1024;

    int nb_c = (E + 256 * ITEMS - 1) / (256 * ITEMS);
    int NB   = (N + 255) / 256;
    int M    = 256 * nb_c;
    int mb   = (M + 255) / 256;
    int nb_s3 = (M + 1 + 255) / 256;

    // workspace layout
    float* h = (float*)d_ws;                                          // N*64 f32
    unsigned short* h_bf = (unsigned short*)(h + (size_t)N * H);      // N*64 bf16
    unsigned short* hnew_bf = h_bf + (size_t)N * H;                   // N*64 bf16
    unsigned short* w_bf = hnew_bf + (size_t)N * H;                   // 2*per bf16
    float* a_gate = (float*)(w_bf + 2 * per);                         // N
    float* b_gate = a_gate + N;                                       // N
    int* offsets  = (int*)(b_gate + N);                               // N+1
    unsigned* pk  = (unsigned*)(offsets + N + 1);                     // E
    unsigned short* csr16 = (unsigned short*)(pk + E);                // E (even)
    int* bhist = (int*)(csr16 + E);                                   // M
    int* bloc  = bhist + M;                                           // M
    int* sbh   = bloc + M;                                            // M+1
    int* bsum  = sbh + M + 1;                                         // mb

    // fused setup: input linear | weight convert | bucket hist
    setup_kernel<<<nb_nodes + nb_conv + nb_c, 256, 0, stream>>>(
        features, W_in, b_in, W_edge, h, h_bf, a_gate, b_gate,
        Wih, Whh, w_bf, dst, bhist,
        N, E, per, nb_nodes, nb_conv, nb_c);

    // CSR build (bucket sort)
    scan_pass1<<<mb, 256, 0, stream>>>(bhist, bloc, bsum, M);
    scan_pass3c<<<nb_s3, 256, 0, stream>>>(bloc, bsum, sbh, M, E, mb);
    bucket_scatter_kernel<<<nb_c, 256, 0, stream>>>(src, dst, sbh, pk, E, nb_c);
    bucket_finalize_kernel<<<NB, 256, 0, stream>>>(pk, sbh, offsets, csr16, N, E, nb_c, NB);

    for (int l = 0; l < L; l++) {
        aggregate_kernel<<<nb_agg, 256, 0, stream>>>(
            h_bf, a_gate, b_gate, offsets, csr16, b_edge, hnew_bf, N);
        const float* Wg = (l < L - 1) ? W_edge : W_pred;
        gru_mfma_kernel<<<nb_gru, 256, 0, stream>>>(
            hnew_bf, h, h_bf,
            w_bf + (size_t)l * H3 * H,
            w_bf + (size_t)per + (size_t)l * H3 * H,
            bih + (size_t)l * H3, bhh + (size_t)l * H3,
            Wg, a_gate, b_gate, N);
    }

    predict_kernel<<<nb_pred, 256, 0, stream>>>(src, dst, a_gate, b_gate, b_pred, out, E);
}